// Round 1
// baseline (1094.106 us; speedup 1.0000x reference)
//
#include <hip/hip_runtime.h>
#include <hip/hip_bf16.h>
#include <math.h>

// Problem constants (from reference)
#define NN 50000
#define EE 400000
#define D_IN 256
#define D_H 64
#define N_CLS 50

// ---------------------------------------------------------------------------
// CSR construction: count in-degree, exclusive scan, fill src lists per dst.
// Edge list = edge_index (E edges) + N self loops (idx >= E -> src=dst=idx-E).
// ---------------------------------------------------------------------------
__global__ void zero_k(int* p, int n) {
    int i = blockIdx.x * blockDim.x + threadIdx.x;
    if (i < n) p[i] = 0;
}

__global__ void count_k(const int* __restrict__ ei, int* __restrict__ cnt, int E, int N) {
    int i = blockIdx.x * blockDim.x + threadIdx.x;
    if (i >= E + N) return;
    int dst = (i < E) ? ei[E + i] : (i - E);
    atomicAdd(&cnt[dst], 1);
}

__global__ __launch_bounds__(1024) void scan_k(const int* __restrict__ counts,
                                               int* __restrict__ rowptr, int n) {
    __shared__ int wsum[16];
    __shared__ int carry_s;
    int t = threadIdx.x;
    int lane = t & 63, wid = t >> 6;
    if (t == 0) carry_s = 0;
    __syncthreads();
    for (int base = 0; base < n; base += 1024) {
        int idx = base + t;
        int v = (idx < n) ? counts[idx] : 0;
        int incl = v;
        #pragma unroll
        for (int off = 1; off < 64; off <<= 1) {
            int x = __shfl_up(incl, off);
            if (lane >= off) incl += x;
        }
        if (lane == 63) wsum[wid] = incl;
        __syncthreads();
        if (wid == 0) {
            int ws = (lane < 16) ? wsum[lane] : 0;
            int wincl = ws;
            #pragma unroll
            for (int off = 1; off < 16; off <<= 1) {
                int x = __shfl_up(wincl, off);
                if (lane >= off) wincl += x;
            }
            if (lane < 16) wsum[lane] = wincl - ws;  // exclusive prefix of wave sums
        }
        __syncthreads();
        int c = carry_s;
        if (idx < n) rowptr[idx] = c + wsum[wid] + (incl - v);
        __syncthreads();
        if (t == 1023) carry_s = c + wsum[15] + incl;  // incl at lane63 of wave15 = wave15 total
        __syncthreads();
    }
    if (t == 0) rowptr[n] = carry_s;
}

__global__ void fill_k(const int* __restrict__ ei, const int* __restrict__ rowptr,
                       int* __restrict__ cursor, int* __restrict__ csr, int E, int N) {
    int i = blockIdx.x * blockDim.x + threadIdx.x;
    if (i >= E + N) return;
    int s, d;
    if (i < E) { s = ei[i]; d = ei[E + i]; }
    else       { s = i - E; d = i - E; }
    int pos = atomicAdd(&cursor[d], 1);
    csr[rowptr[d] + pos] = s;
}

// ---------------------------------------------------------------------------
// fp32 tiled GEMM: C[M,N] = A[M,K] @ B[K,N].  64x64 tile, 4x4 per-thread, BK=16.
// K % 16 == 0, N % 64 == 0 (holds for all our shapes). M guarded.
// ---------------------------------------------------------------------------
__global__ __launch_bounds__(256) void gemm_k(const float* __restrict__ A,
                                              const float* __restrict__ B,
                                              float* __restrict__ C,
                                              int M, int N, int K) {
    __shared__ float As[16][64];   // [k][m]
    __shared__ float Bs[16][64];   // [k][n]
    const int tid = threadIdx.x;
    const int tx = tid & 15;
    const int ty = tid >> 4;
    const int m0 = blockIdx.y * 64;
    const int n0 = blockIdx.x * 64;
    const int lr  = tid >> 2;          // A row within tile (0..63)
    const int lk  = (tid & 3) << 2;    // A k-chunk (0,4,8,12)
    const int bkr = tid >> 4;          // B k row (0..15)
    const int bn  = (tid & 15) << 2;   // B n-chunk
    float acc[4][4] = {};
    for (int k0 = 0; k0 < K; k0 += 16) {
        float4 av = make_float4(0.f, 0.f, 0.f, 0.f);
        if (m0 + lr < M)
            av = *(const float4*)(A + (size_t)(m0 + lr) * K + (k0 + lk));
        float4 bv = *(const float4*)(B + (size_t)(k0 + bkr) * N + (n0 + bn));
        __syncthreads();
        As[lk + 0][lr] = av.x; As[lk + 1][lr] = av.y;
        As[lk + 2][lr] = av.z; As[lk + 3][lr] = av.w;
        *(float4*)&Bs[bkr][bn] = bv;
        __syncthreads();
        #pragma unroll
        for (int kk = 0; kk < 16; kk++) {
            float4 a = *(const float4*)&As[kk][ty << 2];
            float4 b = *(const float4*)&Bs[kk][tx << 2];
            float ar[4] = {a.x, a.y, a.z, a.w};
            float br[4] = {b.x, b.y, b.z, b.w};
            #pragma unroll
            for (int i = 0; i < 4; i++)
                #pragma unroll
                for (int j = 0; j < 4; j++)
                    acc[i][j] = fmaf(ar[i], br[j], acc[i][j]);
        }
    }
    #pragma unroll
    for (int i = 0; i < 4; i++) {
        int row = m0 + (ty << 2) + i;
        if (row < M) {
            float4 v = make_float4(acc[i][0], acc[i][1], acc[i][2], acc[i][3]);
            *(float4*)(C + (size_t)row * N + n0 + (tx << 2)) = v;
        }
    }
}

// ---------------------------------------------------------------------------
// Attention scores: a_s[n,h] = dot(h[n,h,:], att_s[h,:]),  a_d likewise.
// One 64-lane wave per (n,h).
// ---------------------------------------------------------------------------
template <int H>
__global__ __launch_bounds__(256) void att_k(const float* __restrict__ h,
                                             const float* __restrict__ att_s,
                                             const float* __restrict__ att_d,
                                             float* __restrict__ a_s,
                                             float* __restrict__ a_d, int N) {
    int w = (blockIdx.x * blockDim.x + threadIdx.x) >> 6;
    int lane = threadIdx.x & 63;
    if (w >= N * H) return;
    int n = w / H, hh = w % H;
    float v = h[(size_t)n * (H * 64) + hh * 64 + lane];
    float ss = v * att_s[hh * 64 + lane];
    float sd = v * att_d[hh * 64 + lane];
    #pragma unroll
    for (int off = 32; off; off >>= 1) {
        ss += __shfl_xor(ss, off);
        sd += __shfl_xor(sd, off);
    }
    if (lane == 0) { a_s[w] = ss; a_d[w] = sd; }
}

// ---------------------------------------------------------------------------
// Per-dst-node segment softmax + weighted aggregation (+ head-mean + bias +
// BN(eval) + ReLU epilogue for concat=False layers). One 256-thread block per node.
// ---------------------------------------------------------------------------
template <int H, bool MEAN_BN>
__global__ __launch_bounds__(256) void agg_k(
    const float* __restrict__ hfeat,            // [N, H*64]
    const float* __restrict__ a_s, const float* __restrict__ a_d,  // [N,H]
    const int* __restrict__ rowptr, const int* __restrict__ csr,
    const float* __restrict__ bias,
    const float* __restrict__ bn_g, const float* __restrict__ bn_b,
    const float* __restrict__ bn_m, const float* __restrict__ bn_v,
    float* __restrict__ outf, int N) {
    constexpr int OUT = H * 64;
    constexpr int TH = 256 / H;           // threads per head group (phase 1)
    constexpr int REP = (OUT + 255) / 256;
    constexpr int CHUNK = 32;
    __shared__ float emax[H], denom[H];
    __shared__ float red[256];
    __shared__ int srcb[CHUNK];
    __shared__ float alpha[CHUNK][H];
    __shared__ float outbuf[OUT];

    int n = blockIdx.x;
    int t = threadIdx.x;
    int row = rowptr[n];
    int deg = rowptr[n + 1] - row;
    int hh = t / TH;
    int tg = t % TH;
    float adn = a_d[n * H + hh];

    // phase 1a: per-head max of leaky_relu(a_s[src]+a_d[n])
    float lm = -INFINITY;
    for (int j = tg; j < deg; j += TH) {
        int s = csr[row + j];
        float e = a_s[s * H + hh] + adn;
        e = e > 0.f ? e : 0.2f * e;
        lm = fmaxf(lm, e);
    }
    red[t] = lm;
    __syncthreads();
    for (int off = TH / 2; off > 0; off >>= 1) {
        if (tg < off) red[t] = fmaxf(red[t], red[t + off]);
        __syncthreads();
    }
    if (tg == 0) emax[hh] = red[t];
    __syncthreads();
    float em = emax[hh];

    // phase 1b: denom = sum exp(e - emax)
    float ls = 0.f;
    for (int j = tg; j < deg; j += TH) {
        int s = csr[row + j];
        float e = a_s[s * H + hh] + adn;
        e = e > 0.f ? e : 0.2f * e;
        ls += __expf(e - em);
    }
    red[t] = ls;
    __syncthreads();
    for (int off = TH / 2; off > 0; off >>= 1) {
        if (tg < off) red[t] += red[t + off];
        __syncthreads();
    }
    if (tg == 0) denom[hh] = red[t] + 1e-16f;
    __syncthreads();

    // phase 2: out[h,c] = sum_e alpha[e,h] * hfeat[src_e, h, c]
    float acc[REP] = {};
    for (int base = 0; base < deg; base += CHUNK) {
        int cnt = min(CHUNK, deg - base);
        __syncthreads();   // protect srcb/alpha from previous chunk's readers
        if (t < cnt) srcb[t] = csr[row + base + t];
        __syncthreads();
        for (int idx = t; idx < cnt * H; idx += 256) {
            int j = idx / H;
            int h2 = idx % H;
            float e = a_s[srcb[j] * H + h2] + a_d[n * H + h2];
            e = e > 0.f ? e : 0.2f * e;
            alpha[j][h2] = __expf(e - emax[h2]) / denom[h2];
        }
        __syncthreads();
        #pragma unroll
        for (int r = 0; r < REP; r++) {
            int o = t + r * 256;
            if (OUT >= 256 || t < OUT) {
                int oh = o >> 6;
                for (int j = 0; j < cnt; j++)
                    acc[r] = fmaf(alpha[j][oh], hfeat[(size_t)srcb[j] * OUT + o], acc[r]);
            }
        }
    }

    if (MEAN_BN) {
        #pragma unroll
        for (int r = 0; r < REP; r++) {
            int o = t + r * 256;
            if (OUT >= 256 || t < OUT) outbuf[o] = acc[r];
        }
        __syncthreads();
        if (t < 64) {
            float s = 0.f;
            #pragma unroll
            for (int h2 = 0; h2 < H; h2++) s += outbuf[h2 * 64 + t];
            s = s * (1.0f / H) + bias[t];
            s = (s - bn_m[t]) * bn_g[t] * rsqrtf(bn_v[t] + 1e-5f) + bn_b[t];
            s = fmaxf(s, 0.f);
            outf[(size_t)n * 64 + t] = s;
        }
    } else {
        if (t < 64) outf[(size_t)n * 64 + t] = acc[0] + bias[t];
    }
}

// ---------------------------------------------------------------------------
// Classifier: z = relu(h@cW1+cb1); logits = z@cW2+cb2; softmax. Wave per node.
// ---------------------------------------------------------------------------
__global__ __launch_bounds__(256) void cls_k(const float* __restrict__ feat,
                                             const float* __restrict__ cW1,
                                             const float* __restrict__ cb1,
                                             const float* __restrict__ cW2,
                                             const float* __restrict__ cb2,
                                             float* __restrict__ out, int N) {
    int lane = threadIdx.x & 63;
    int n = (blockIdx.x * blockDim.x + threadIdx.x) >> 6;
    if (n >= N) return;
    float hv = feat[(size_t)n * 64 + lane];
    float z = cb1[lane];
    #pragma unroll
    for (int k = 0; k < 64; k++) {
        float a = __shfl(hv, k);
        z = fmaf(a, cW1[k * 64 + lane], z);
    }
    z = fmaxf(z, 0.f);
    float lg = (lane < N_CLS) ? cb2[lane] : -INFINITY;
    #pragma unroll
    for (int k = 0; k < 64; k++) {
        float a = __shfl(z, k);
        if (lane < N_CLS) lg = fmaf(a, cW2[k * N_CLS + lane], lg);
    }
    float m = lg;
    #pragma unroll
    for (int off = 32; off; off >>= 1) m = fmaxf(m, __shfl_xor(m, off));
    float p = (lane < N_CLS) ? __expf(lg - m) : 0.f;
    float s = p;
    #pragma unroll
    for (int off = 32; off; off >>= 1) s += __shfl_xor(s, off);
    if (lane < N_CLS) out[(size_t)n * N_CLS + lane] = p / s;
}

// ---------------------------------------------------------------------------
extern "C" void kernel_launch(void* const* d_in, const int* in_sizes, int n_in,
                              void* d_out, int out_size, void* d_ws, size_t ws_size,
                              hipStream_t stream) {
    const int N = NN, E = EE, E2 = EE + NN;
    const float* x    = (const float*)d_in[0];
    const int*   ei   = (const int*)d_in[1];
    const float* W1   = (const float*)d_in[2];
    const float* as1  = (const float*)d_in[3];
    const float* ad1  = (const float*)d_in[4];
    const float* b1   = (const float*)d_in[5];
    const float* W2   = (const float*)d_in[6];
    const float* as2  = (const float*)d_in[7];
    const float* ad2  = (const float*)d_in[8];
    const float* b2   = (const float*)d_in[9];
    const float* W3   = (const float*)d_in[10];
    const float* as3  = (const float*)d_in[11];
    const float* ad3  = (const float*)d_in[12];
    const float* b3   = (const float*)d_in[13];
    const float* bn1g = (const float*)d_in[14];
    const float* bn1b = (const float*)d_in[15];
    const float* bn1m = (const float*)d_in[16];
    const float* bn1v = (const float*)d_in[17];
    const float* bn2g = (const float*)d_in[18];
    const float* bn2b = (const float*)d_in[19];
    const float* bn2m = (const float*)d_in[20];
    const float* bn2v = (const float*)d_in[21];
    const float* cW1  = (const float*)d_in[22];
    const float* cb1  = (const float*)d_in[23];
    const float* cW2  = (const float*)d_in[24];
    const float* cb2  = (const float*)d_in[25];
    float* out = (float*)d_out;

    char* ws = (char*)d_ws;
    size_t off = 0;
    auto alloc = [&](size_t bytes) {
        void* p = ws + off;
        off = (off + bytes + 255) & ~(size_t)255;
        return p;
    };
    int*   rowptr = (int*)alloc((size_t)(N + 1) * 4);
    int*   cursor = (int*)alloc((size_t)N * 4);
    int*   csr    = (int*)alloc((size_t)E2 * 4);
    float* hbig   = (float*)alloc((size_t)N * 512 * 4);
    float* asb    = (float*)alloc((size_t)N * 8 * 4);
    float* adb    = (float*)alloc((size_t)N * 8 * 4);
    float* f1     = (float*)alloc((size_t)N * 64 * 4);
    float* f2     = (float*)alloc((size_t)N * 64 * 4);
    float* f3     = (float*)alloc((size_t)N * 64 * 4);

    // ---- CSR build (shared by all 3 layers) ----
    zero_k<<<(N + 255) / 256, 256, 0, stream>>>(cursor, N);
    count_k<<<(E2 + 255) / 256, 256, 0, stream>>>(ei, cursor, E, N);
    scan_k<<<1, 1024, 0, stream>>>(cursor, rowptr, N);
    zero_k<<<(N + 255) / 256, 256, 0, stream>>>(cursor, N);
    fill_k<<<(E2 + 255) / 256, 256, 0, stream>>>(ei, rowptr, cursor, csr, E, N);

    // ---- Layer 1: heads=8, in=256, concat=False + BN1 + ReLU ----
    gemm_k<<<dim3(512 / 64, (N + 63) / 64), 256, 0, stream>>>(x, W1, hbig, N, 512, 256);
    att_k<8><<<((size_t)N * 8 * 64 + 255) / 256, 256, 0, stream>>>(hbig, as1, ad1, asb, adb, N);
    agg_k<8, true><<<N, 256, 0, stream>>>(hbig, asb, adb, rowptr, csr, b1,
                                          bn1g, bn1b, bn1m, bn1v, f1, N);

    // ---- Layer 2: heads=4, in=64, concat=False + BN2 + ReLU ----
    gemm_k<<<dim3(256 / 64, (N + 63) / 64), 256, 0, stream>>>(f1, W2, hbig, N, 256, 64);
    att_k<4><<<((size_t)N * 4 * 64 + 255) / 256, 256, 0, stream>>>(hbig, as2, ad2, asb, adb, N);
    agg_k<4, true><<<N, 256, 0, stream>>>(hbig, asb, adb, rowptr, csr, b2,
                                          bn2g, bn2b, bn2m, bn2v, f2, N);

    // ---- Layer 3: heads=1, in=64, concat=True ----
    gemm_k<<<dim3(1, (N + 63) / 64), 256, 0, stream>>>(f2, W3, hbig, N, 64, 64);
    att_k<1><<<((size_t)N * 1 * 64 + 255) / 256, 256, 0, stream>>>(hbig, as3, ad3, asb, adb, N);
    agg_k<1, false><<<N, 256, 0, stream>>>(hbig, asb, adb, rowptr, csr, b3,
                                           nullptr, nullptr, nullptr, nullptr, f3, N);

    // ---- Classifier + softmax ----
    cls_k<<<(N + 3) / 4, 256, 0, stream>>>(f3, cW1, cb1, cW2, cb2, out, N);
}

// Round 2
// 1022.003 us; speedup vs baseline: 1.0706x; 1.0706x over previous
//
#include <hip/hip_runtime.h>
#include <hip/hip_bf16.h>
#include <math.h>

#define NN 50000
#define EE 400000
#define D_IN 256
#define D_H 64
#define N_CLS 50

typedef __attribute__((ext_vector_type(8))) short bfrag;   // 8 bf16 (4 VGPR)
typedef __attribute__((ext_vector_type(4))) float ffrag;   // MFMA C/D

__device__ __forceinline__ unsigned short f2bf(float v) {
    unsigned int u = __float_as_uint(v);
    unsigned int r = (u + 0x7fffu + ((u >> 16) & 1u)) >> 16;   // RNE
    return (unsigned short)r;
}
__device__ __forceinline__ float bf2f(unsigned short b) {
    return __uint_as_float(((unsigned int)b) << 16);
}

// ---------------------------------------------------------------------------
// CSR construction (unchanged from round 0 — verified)
// ---------------------------------------------------------------------------
__global__ void zero_k(int* p, int n) {
    int i = blockIdx.x * blockDim.x + threadIdx.x;
    if (i < n) p[i] = 0;
}

__global__ void count_k(const int* __restrict__ ei, int* __restrict__ cnt, int E, int N) {
    int i = blockIdx.x * blockDim.x + threadIdx.x;
    if (i >= E + N) return;
    int dst = (i < E) ? ei[E + i] : (i - E);
    atomicAdd(&cnt[dst], 1);
}

__global__ __launch_bounds__(1024) void scan_k(const int* __restrict__ counts,
                                               int* __restrict__ rowptr, int n) {
    __shared__ int wsum[16];
    __shared__ int carry_s;
    int t = threadIdx.x;
    int lane = t & 63, wid = t >> 6;
    if (t == 0) carry_s = 0;
    __syncthreads();
    for (int base = 0; base < n; base += 1024) {
        int idx = base + t;
        int v = (idx < n) ? counts[idx] : 0;
        int incl = v;
        #pragma unroll
        for (int off = 1; off < 64; off <<= 1) {
            int x = __shfl_up(incl, off);
            if (lane >= off) incl += x;
        }
        if (lane == 63) wsum[wid] = incl;
        __syncthreads();
        if (wid == 0) {
            int ws = (lane < 16) ? wsum[lane] : 0;
            int wincl = ws;
            #pragma unroll
            for (int off = 1; off < 16; off <<= 1) {
                int x = __shfl_up(wincl, off);
                if (lane >= off) wincl += x;
            }
            if (lane < 16) wsum[lane] = wincl - ws;
        }
        __syncthreads();
        int c = carry_s;
        if (idx < n) rowptr[idx] = c + wsum[wid] + (incl - v);
        __syncthreads();
        if (t == 1023) carry_s = c + wsum[15] + incl;
        __syncthreads();
    }
    if (t == 0) rowptr[n] = carry_s;
}

__global__ void fill_k(const int* __restrict__ ei, const int* __restrict__ rowptr,
                       int* __restrict__ cursor, int* __restrict__ csr, int E, int N) {
    int i = blockIdx.x * blockDim.x + threadIdx.x;
    if (i >= E + N) return;
    int s, d;
    if (i < E) { s = ei[i]; d = ei[E + i]; }
    else       { s = i - E; d = i - E; }
    int pos = atomicAdd(&cursor[d], 1);
    csr[rowptr[d] + pos] = s;
}

// ---------------------------------------------------------------------------
// Split-bf16 conversion: A (row-major, flat) and B -> B^T (for MFMA B-frags)
// ---------------------------------------------------------------------------
__global__ void cvt_a_k(const float* __restrict__ a, unsigned short* __restrict__ hi,
                        unsigned short* __restrict__ lo, int n) {
    int i = blockIdx.x * 256 + threadIdx.x;
    if (i >= n) return;
    float v = a[i];
    unsigned short h = f2bf(v);
    hi[i] = h;
    lo[i] = f2bf(v - bf2f(h));
}

__global__ void cvt_bt_k(const float* __restrict__ Bsrc, unsigned short* __restrict__ hi,
                         unsigned short* __restrict__ lo, int K, int N) {
    int i = blockIdx.x * 256 + threadIdx.x;
    if (i >= K * N) return;
    int k = i / N, n = i % N;
    float v = Bsrc[i];
    unsigned short h = f2bf(v);
    hi[(size_t)n * K + k] = h;
    lo[(size_t)n * K + k] = f2bf(v - bf2f(h));
}

// ---------------------------------------------------------------------------
// Split-bf16 MFMA GEMM: C[M,N] = A[M,K] @ B[K,N], B passed as B^T hi/lo.
// Block tile 64(M)x128(N), BK=32. 4 waves in 2x2; wave tile 32x64 =
// 2x4 of 16x16x32 MFMAs, 3 products (hi*hi, hi*lo, lo*hi) per tile.
// Requires K%32==0, N%64==0 handled via clamp+guard. M guarded.
// ---------------------------------------------------------------------------
__global__ __launch_bounds__(256) void gemm_mfma_k(
    const unsigned short* __restrict__ Ahi, const unsigned short* __restrict__ Alo,
    const unsigned short* __restrict__ BThi, const unsigned short* __restrict__ BTlo,
    float* __restrict__ C, int M, int N, int K) {
    __shared__ unsigned short sA[2][64][40];    // [hi/lo][m][k]  pad 32->40
    __shared__ unsigned short sB[2][128][40];   // [hi/lo][n][k]
    const int tid = threadIdx.x;
    const int m0 = blockIdx.y * 64;
    const int n0 = blockIdx.x * 128;
    const int lane = tid & 63, w = tid >> 6;
    const int wm = w >> 1, wn = w & 1;
    const int c16 = lane & 15, kq = lane >> 4;
    const int arow = tid >> 2;          // 0..63
    const int akc  = (tid & 3) * 8;     // 0,8,16,24
    const int aM  = min(m0 + arow, M - 1);
    const int bn0 = min(n0 + arow, N - 1);
    const int bn1 = min(n0 + 64 + arow, N - 1);
    ffrag acc[2][4] = {};

    for (int k0 = 0; k0 < K; k0 += 32) {
        bfrag va_h  = *(const bfrag*)(Ahi  + (size_t)aM  * K + k0 + akc);
        bfrag va_l  = *(const bfrag*)(Alo  + (size_t)aM  * K + k0 + akc);
        bfrag vb_h0 = *(const bfrag*)(BThi + (size_t)bn0 * K + k0 + akc);
        bfrag vb_l0 = *(const bfrag*)(BTlo + (size_t)bn0 * K + k0 + akc);
        bfrag vb_h1 = *(const bfrag*)(BThi + (size_t)bn1 * K + k0 + akc);
        bfrag vb_l1 = *(const bfrag*)(BTlo + (size_t)bn1 * K + k0 + akc);
        __syncthreads();
        *(bfrag*)&sA[0][arow][akc]      = va_h;
        *(bfrag*)&sA[1][arow][akc]      = va_l;
        *(bfrag*)&sB[0][arow][akc]      = vb_h0;
        *(bfrag*)&sB[1][arow][akc]      = vb_l0;
        *(bfrag*)&sB[0][64 + arow][akc] = vb_h1;
        *(bfrag*)&sB[1][64 + arow][akc] = vb_l1;
        __syncthreads();
        bfrag ah[2], al_[2], bh[4], bl[4];
        #pragma unroll
        for (int mt = 0; mt < 2; mt++) {
            ah[mt]  = *(const bfrag*)&sA[0][wm * 32 + mt * 16 + c16][kq * 8];
            al_[mt] = *(const bfrag*)&sA[1][wm * 32 + mt * 16 + c16][kq * 8];
        }
        #pragma unroll
        for (int nt = 0; nt < 4; nt++) {
            bh[nt] = *(const bfrag*)&sB[0][wn * 64 + nt * 16 + c16][kq * 8];
            bl[nt] = *(const bfrag*)&sB[1][wn * 64 + nt * 16 + c16][kq * 8];
        }
        #pragma unroll
        for (int mt = 0; mt < 2; mt++)
            #pragma unroll
            for (int nt = 0; nt < 4; nt++) {
                acc[mt][nt] = __builtin_amdgcn_mfma_f32_16x16x32_bf16(ah[mt],  bh[nt], acc[mt][nt], 0, 0, 0);
                acc[mt][nt] = __builtin_amdgcn_mfma_f32_16x16x32_bf16(ah[mt],  bl[nt], acc[mt][nt], 0, 0, 0);
                acc[mt][nt] = __builtin_amdgcn_mfma_f32_16x16x32_bf16(al_[mt], bh[nt], acc[mt][nt], 0, 0, 0);
            }
    }
    // epilogue: D row = kq*4 + reg, col = c16 (m89-verified layout)
    #pragma unroll
    for (int mt = 0; mt < 2; mt++) {
        #pragma unroll
        for (int r = 0; r < 4; r++) {
            int row = m0 + wm * 32 + mt * 16 + kq * 4 + r;
            if (row < M) {
                #pragma unroll
                for (int nt = 0; nt < 4; nt++) {
                    int col = n0 + wn * 64 + nt * 16 + c16;
                    if (col < N) C[(size_t)row * N + col] = acc[mt][nt][r];
                }
            }
        }
    }
}

// ---------------------------------------------------------------------------
// Attention scores (unchanged)
// ---------------------------------------------------------------------------
template <int H>
__global__ __launch_bounds__(256) void att_k(const float* __restrict__ h,
                                             const float* __restrict__ att_s,
                                             const float* __restrict__ att_d,
                                             float* __restrict__ a_s,
                                             float* __restrict__ a_d, int N) {
    int w = (blockIdx.x * blockDim.x + threadIdx.x) >> 6;
    int lane = threadIdx.x & 63;
    if (w >= N * H) return;
    int n = w / H, hh = w % H;
    float v = h[(size_t)n * (H * 64) + hh * 64 + lane];
    float ss = v * att_s[hh * 64 + lane];
    float sd = v * att_d[hh * 64 + lane];
    #pragma unroll
    for (int off = 32; off; off >>= 1) {
        ss += __shfl_xor(ss, off);
        sd += __shfl_xor(sd, off);
    }
    if (lane == 0) { a_s[w] = ss; a_d[w] = sd; }
}

__device__ __forceinline__ float wave_max_f(float v) {
    #pragma unroll
    for (int off = 32; off; off >>= 1) v = fmaxf(v, __shfl_xor(v, off));
    return v;
}
__device__ __forceinline__ float wave_sum_f(float v) {
    #pragma unroll
    for (int off = 32; off; off >>= 1) v += __shfl_xor(v, off);
    return v;
}

// ---------------------------------------------------------------------------
// Segment softmax + aggregation: ONE WAVE per (node, head).
// alpha/src broadcast via v_readlane (SGPR) — no LDS in the gather loop;
// each edge = one coalesced 256B row read + one FMA per lane.
// ---------------------------------------------------------------------------
template <int H, int NPB, bool MEAN_BN>
__global__ __launch_bounds__(64 * H * NPB) void agg_k(
    const float* __restrict__ hfeat,
    const float* __restrict__ a_s, const float* __restrict__ a_d,
    const int* __restrict__ rowptr, const int* __restrict__ csr,
    const float* __restrict__ bias,
    const float* __restrict__ bn_g, const float* __restrict__ bn_b,
    const float* __restrict__ bn_m, const float* __restrict__ bn_v,
    float* __restrict__ outf, int N) {
    constexpr int OUT = H * 64;
    const int ww = threadIdx.x >> 6;
    const int lane = threadIdx.x & 63;
    const int node = (NPB == 1) ? (int)blockIdx.x : (int)(blockIdx.x * NPB + ww);
    const int h = (NPB == 1) ? ww : 0;
    float acc = 0.f;
    if (node < N) {
        int row = rowptr[node];
        int deg = rowptr[node + 1] - row;
        float adn = a_d[node * H + h];
        const float* hcol = hfeat + (size_t)h * 64 + lane;
        if (deg <= 64) {
            int s = (lane < deg) ? csr[row + lane] : 0;
            float e = -INFINITY;
            if (lane < deg) {
                e = a_s[s * H + h] + adn;
                e = e > 0.f ? e : 0.2f * e;
            }
            float m = wave_max_f(e);
            float p = (lane < deg) ? __expf(e - m) : 0.f;
            float denom = wave_sum_f(p) + 1e-16f;
            float pd = p / denom;
            for (int j = 0; j < deg; j++) {
                float al = __int_as_float(__builtin_amdgcn_readlane(__float_as_int(pd), j));
                int ss = __builtin_amdgcn_readlane(s, j);
                acc = fmaf(al, hcol[(size_t)ss * OUT], acc);
            }
        } else {
            float m = -INFINITY;
            for (int c0 = 0; c0 < deg; c0 += 64) {
                int j = c0 + lane;
                if (j < deg) {
                    int s2 = csr[row + j];
                    float e = a_s[s2 * H + h] + adn;
                    e = e > 0.f ? e : 0.2f * e;
                    m = fmaxf(m, e);
                }
            }
            m = wave_max_f(m);
            float dsum = 0.f;
            for (int c0 = 0; c0 < deg; c0 += 64) {
                int j = c0 + lane;
                if (j < deg) {
                    int s2 = csr[row + j];
                    float e = a_s[s2 * H + h] + adn;
                    e = e > 0.f ? e : 0.2f * e;
                    dsum += __expf(e - m);
                }
            }
            float denom = wave_sum_f(dsum) + 1e-16f;
            for (int c0 = 0; c0 < deg; c0 += 64) {
                int j = c0 + lane;
                int s = 0; float p = 0.f;
                if (j < deg) {
                    s = csr[row + j];
                    float e = a_s[s * H + h] + adn;
                    e = e > 0.f ? e : 0.2f * e;
                    p = __expf(e - m) / denom;
                }
                int cnt = min(64, deg - c0);
                for (int jj = 0; jj < cnt; jj++) {
                    float al = __int_as_float(__builtin_amdgcn_readlane(__float_as_int(p), jj));
                    int ss = __builtin_amdgcn_readlane(s, jj);
                    acc = fmaf(al, hcol[(size_t)ss * OUT], acc);
                }
            }
        }
    }
    if (MEAN_BN) {
        __shared__ float sh[H][64];
        sh[h][lane] = acc;
        __syncthreads();
        if (threadIdx.x < 64) {
            int t = threadIdx.x;
            float sum = 0.f;
            #pragma unroll
            for (int h2 = 0; h2 < H; h2++) sum += sh[h2][t];
            float v = sum * (1.0f / H) + bias[t];
            v = (v - bn_m[t]) * bn_g[t] * rsqrtf(bn_v[t] + 1e-5f) + bn_b[t];
            outf[(size_t)node * 64 + t] = fmaxf(v, 0.f);
        }
    } else {
        if (node < N) outf[(size_t)node * 64 + lane] = acc + bias[lane];
    }
}

// ---------------------------------------------------------------------------
// Classifier + softmax (unchanged)
// ---------------------------------------------------------------------------
__global__ __launch_bounds__(256) void cls_k(const float* __restrict__ feat,
                                             const float* __restrict__ cW1,
                                             const float* __restrict__ cb1,
                                             const float* __restrict__ cW2,
                                             const float* __restrict__ cb2,
                                             float* __restrict__ out, int N) {
    int lane = threadIdx.x & 63;
    int n = (blockIdx.x * blockDim.x + threadIdx.x) >> 6;
    if (n >= N) return;
    float hv = feat[(size_t)n * 64 + lane];
    float z = cb1[lane];
    #pragma unroll
    for (int k = 0; k < 64; k++) {
        float a = __shfl(hv, k);
        z = fmaf(a, cW1[k * 64 + lane], z);
    }
    z = fmaxf(z, 0.f);
    float lg = (lane < N_CLS) ? cb2[lane] : -INFINITY;
    #pragma unroll
    for (int k = 0; k < 64; k++) {
        float a = __shfl(z, k);
        if (lane < N_CLS) lg = fmaf(a, cW2[k * N_CLS + lane], lg);
    }
    float m = lg;
    #pragma unroll
    for (int off = 32; off; off >>= 1) m = fmaxf(m, __shfl_xor(m, off));
    float p = (lane < N_CLS) ? __expf(lg - m) : 0.f;
    float s = p;
    #pragma unroll
    for (int off = 32; off; off >>= 1) s += __shfl_xor(s, off);
    if (lane < N_CLS) out[(size_t)n * N_CLS + lane] = p / s;
}

// ---------------------------------------------------------------------------
extern "C" void kernel_launch(void* const* d_in, const int* in_sizes, int n_in,
                              void* d_out, int out_size, void* d_ws, size_t ws_size,
                              hipStream_t stream) {
    const int N = NN, E = EE, E2 = EE + NN;
    const float* x    = (const float*)d_in[0];
    const int*   ei   = (const int*)d_in[1];
    const float* W1   = (const float*)d_in[2];
    const float* as1  = (const float*)d_in[3];
    const float* ad1  = (const float*)d_in[4];
    const float* b1   = (const float*)d_in[5];
    const float* W2   = (const float*)d_in[6];
    const float* as2  = (const float*)d_in[7];
    const float* ad2  = (const float*)d_in[8];
    const float* b2   = (const float*)d_in[9];
    const float* W3   = (const float*)d_in[10];
    const float* as3  = (const float*)d_in[11];
    const float* ad3  = (const float*)d_in[12];
    const float* b3   = (const float*)d_in[13];
    const float* bn1g = (const float*)d_in[14];
    const float* bn1b = (const float*)d_in[15];
    const float* bn1m = (const float*)d_in[16];
    const float* bn1v = (const float*)d_in[17];
    const float* bn2g = (const float*)d_in[18];
    const float* bn2b = (const float*)d_in[19];
    const float* bn2m = (const float*)d_in[20];
    const float* bn2v = (const float*)d_in[21];
    const float* cW1  = (const float*)d_in[22];
    const float* cb1  = (const float*)d_in[23];
    const float* cW2  = (const float*)d_in[24];
    const float* cb2  = (const float*)d_in[25];
    float* out = (float*)d_out;

    char* ws = (char*)d_ws;
    size_t off = 0;
    auto alloc = [&](size_t bytes) {
        void* p = ws + off;
        off = (off + bytes + 255) & ~(size_t)255;
        return p;
    };
    int*   rowptr = (int*)alloc((size_t)(N + 1) * 4);
    int*   cursor = (int*)alloc((size_t)N * 4);
    int*   csr    = (int*)alloc((size_t)E2 * 4);
    float* hbig   = (float*)alloc((size_t)N * 512 * 4);
    float* asb    = (float*)alloc((size_t)N * 8 * 4);
    float* adb    = (float*)alloc((size_t)N * 8 * 4);
    float* f1     = (float*)alloc((size_t)N * 64 * 4);   // also reused as f3
    float* f2     = (float*)alloc((size_t)N * 64 * 4);
    unsigned short* ahi = (unsigned short*)alloc((size_t)N * D_IN * 2);
    unsigned short* alo = (unsigned short*)alloc((size_t)N * D_IN * 2);
    unsigned short* wthi = (unsigned short*)alloc((size_t)512 * 256 * 2);
    unsigned short* wtlo = (unsigned short*)alloc((size_t)512 * 256 * 2);
    float* f3 = f1;

    // ---- CSR build (shared by all 3 layers) ----
    zero_k<<<(N + 255) / 256, 256, 0, stream>>>(cursor, N);
    count_k<<<(E2 + 255) / 256, 256, 0, stream>>>(ei, cursor, E, N);
    scan_k<<<1, 1024, 0, stream>>>(cursor, rowptr, N);
    zero_k<<<(N + 255) / 256, 256, 0, stream>>>(cursor, N);
    fill_k<<<(E2 + 255) / 256, 256, 0, stream>>>(ei, rowptr, cursor, csr, E, N);

    const int MB = (N + 63) / 64;

    // ---- Layer 1: heads=8, in=256, concat=False + BN1 + ReLU ----
    cvt_a_k<<<((size_t)N * 256 + 255) / 256, 256, 0, stream>>>(x, ahi, alo, N * 256);
    cvt_bt_k<<<(256 * 512 + 255) / 256, 256, 0, stream>>>(W1, wthi, wtlo, 256, 512);
    gemm_mfma_k<<<dim3(4, MB), 256, 0, stream>>>(ahi, alo, wthi, wtlo, hbig, N, 512, 256);
    att_k<8><<<((size_t)N * 8 * 64 + 255) / 256, 256, 0, stream>>>(hbig, as1, ad1, asb, adb, N);
    agg_k<8, 1, true><<<N, 512, 0, stream>>>(hbig, asb, adb, rowptr, csr, b1,
                                             bn1g, bn1b, bn1m, bn1v, f1, N);

    // ---- Layer 2: heads=4, in=64, concat=False + BN2 + ReLU ----
    cvt_a_k<<<((size_t)N * 64 + 255) / 256, 256, 0, stream>>>(f1, ahi, alo, N * 64);
    cvt_bt_k<<<(64 * 256 + 255) / 256, 256, 0, stream>>>(W2, wthi, wtlo, 64, 256);
    gemm_mfma_k<<<dim3(2, MB), 256, 0, stream>>>(ahi, alo, wthi, wtlo, hbig, N, 256, 64);
    att_k<4><<<((size_t)N * 4 * 64 + 255) / 256, 256, 0, stream>>>(hbig, as2, ad2, asb, adb, N);
    agg_k<4, 1, true><<<N, 256, 0, stream>>>(hbig, asb, adb, rowptr, csr, b2,
                                             bn2g, bn2b, bn2m, bn2v, f2, N);

    // ---- Layer 3: heads=1, in=64, concat=True ----
    cvt_a_k<<<((size_t)N * 64 + 255) / 256, 256, 0, stream>>>(f2, ahi, alo, N * 64);
    cvt_bt_k<<<(64 * 64 + 255) / 256, 256, 0, stream>>>(W3, wthi, wtlo, 64, 64);
    gemm_mfma_k<<<dim3(1, MB), 256, 0, stream>>>(ahi, alo, wthi, wtlo, hbig, N, 64, 64);
    att_k<1><<<((size_t)N * 1 * 64 + 255) / 256, 256, 0, stream>>>(hbig, as3, ad3, asb, adb, N);
    agg_k<1, 4, false><<<(N + 3) / 4, 256, 0, stream>>>(hbig, asb, adb, rowptr, csr, b3,
                                                        nullptr, nullptr, nullptr, nullptr, f3, N);

    // ---- Classifier + softmax ----
    cls_k<<<(N + 3) / 4, 256, 0, stream>>>(f3, cW1, cb1, cW2, cb2, out, N);
}

// Round 3
// 852.539 us; speedup vs baseline: 1.2834x; 1.1988x over previous
//
#include <hip/hip_runtime.h>
#include <hip/hip_bf16.h>
#include <math.h>

#define NN 50000
#define EE 400000
#define D_IN 256
#define D_H 64
#define N_CLS 50

typedef __attribute__((ext_vector_type(8))) short bfrag;   // 8 bf16 (4 VGPR)
typedef __attribute__((ext_vector_type(4))) float ffrag;   // MFMA C/D

__device__ __forceinline__ unsigned short f2bf(float v) {
    unsigned int u = __float_as_uint(v);
    unsigned int r = (u + 0x7fffu + ((u >> 16) & 1u)) >> 16;   // RNE
    return (unsigned short)r;
}
__device__ __forceinline__ float bf2f(unsigned short b) {
    return __uint_as_float(((unsigned int)b) << 16);
}

// ---------------------------------------------------------------------------
// CSR construction (verified round 0)
// ---------------------------------------------------------------------------
__global__ void zero_k(int* p, int n) {
    int i = blockIdx.x * blockDim.x + threadIdx.x;
    if (i < n) p[i] = 0;
}

__global__ void count_k(const int* __restrict__ ei, int* __restrict__ cnt, int E, int N) {
    int i = blockIdx.x * blockDim.x + threadIdx.x;
    if (i >= E + N) return;
    int dst = (i < E) ? ei[E + i] : (i - E);
    atomicAdd(&cnt[dst], 1);
}

__global__ __launch_bounds__(1024) void scan_k(const int* __restrict__ counts,
                                               int* __restrict__ rowptr, int n) {
    __shared__ int wsum[16];
    __shared__ int carry_s;
    int t = threadIdx.x;
    int lane = t & 63, wid = t >> 6;
    if (t == 0) carry_s = 0;
    __syncthreads();
    for (int base = 0; base < n; base += 1024) {
        int idx = base + t;
        int v = (idx < n) ? counts[idx] : 0;
        int incl = v;
        #pragma unroll
        for (int off = 1; off < 64; off <<= 1) {
            int x = __shfl_up(incl, off);
            if (lane >= off) incl += x;
        }
        if (lane == 63) wsum[wid] = incl;
        __syncthreads();
        if (wid == 0) {
            int ws = (lane < 16) ? wsum[lane] : 0;
            int wincl = ws;
            #pragma unroll
            for (int off = 1; off < 16; off <<= 1) {
                int x = __shfl_up(wincl, off);
                if (lane >= off) wincl += x;
            }
            if (lane < 16) wsum[lane] = wincl - ws;
        }
        __syncthreads();
        int c = carry_s;
        if (idx < n) rowptr[idx] = c + wsum[wid] + (incl - v);
        __syncthreads();
        if (t == 1023) carry_s = c + wsum[15] + incl;
        __syncthreads();
    }
    if (t == 0) rowptr[n] = carry_s;
}

__global__ void fill_k(const int* __restrict__ ei, const int* __restrict__ rowptr,
                       int* __restrict__ cursor, int* __restrict__ csr, int E, int N) {
    int i = blockIdx.x * blockDim.x + threadIdx.x;
    if (i >= E + N) return;
    int s, d;
    if (i < E) { s = ei[i]; d = ei[E + i]; }
    else       { s = i - E; d = i - E; }
    int pos = atomicAdd(&cursor[d], 1);
    csr[rowptr[d] + pos] = s;
}

// ---------------------------------------------------------------------------
// Split-bf16 conversion kernels
// ---------------------------------------------------------------------------
__global__ void cvt_a_k(const float* __restrict__ a, unsigned short* __restrict__ hi,
                        unsigned short* __restrict__ lo, int n) {
    int i = blockIdx.x * 256 + threadIdx.x;
    if (i >= n) return;
    float v = a[i];
    unsigned short h = f2bf(v);
    hi[i] = h;
    lo[i] = f2bf(v - bf2f(h));
}

__global__ void cvt_bt_k(const float* __restrict__ Bsrc, unsigned short* __restrict__ hi,
                         unsigned short* __restrict__ lo, int K, int N) {
    int i = blockIdx.x * 256 + threadIdx.x;
    if (i >= K * N) return;
    int k = i / N, n = i % N;
    float v = Bsrc[i];
    unsigned short h = f2bf(v);
    hi[(size_t)n * K + k] = h;
    lo[(size_t)n * K + k] = f2bf(v - bf2f(h));
}

// BN folding: scale = g*rsqrt(v+eps); shift = (bias - m)*scale + b
__global__ void bnprep_k(const float* __restrict__ g, const float* __restrict__ b,
                         const float* __restrict__ m, const float* __restrict__ v,
                         const float* __restrict__ bias,
                         float* __restrict__ scale, float* __restrict__ shift) {
    int t = threadIdx.x;
    if (t < 64) {
        float sc = g[t] * rsqrtf(v[t] + 1e-5f);
        scale[t] = sc;
        shift[t] = (bias[t] - m[t]) * sc + b[t];
    }
}

// ---------------------------------------------------------------------------
// Split-bf16 MFMA GEMM (verified round 2): C[M,N] = A @ B, B passed as B^T.
// ---------------------------------------------------------------------------
__global__ __launch_bounds__(256) void gemm_mfma_k(
    const unsigned short* __restrict__ Ahi, const unsigned short* __restrict__ Alo,
    const unsigned short* __restrict__ BThi, const unsigned short* __restrict__ BTlo,
    float* __restrict__ C, int M, int N, int K) {
    __shared__ unsigned short sA[2][64][40];
    __shared__ unsigned short sB[2][128][40];
    const int tid = threadIdx.x;
    const int m0 = blockIdx.y * 64;
    const int n0 = blockIdx.x * 128;
    const int lane = tid & 63, w = tid >> 6;
    const int wm = w >> 1, wn = w & 1;
    const int c16 = lane & 15, kq = lane >> 4;
    const int arow = tid >> 2;
    const int akc  = (tid & 3) * 8;
    const int aM  = min(m0 + arow, M - 1);
    const int bn0 = min(n0 + arow, N - 1);
    const int bn1 = min(n0 + 64 + arow, N - 1);
    ffrag acc[2][4] = {};

    for (int k0 = 0; k0 < K; k0 += 32) {
        bfrag va_h  = *(const bfrag*)(Ahi  + (size_t)aM  * K + k0 + akc);
        bfrag va_l  = *(const bfrag*)(Alo  + (size_t)aM  * K + k0 + akc);
        bfrag vb_h0 = *(const bfrag*)(BThi + (size_t)bn0 * K + k0 + akc);
        bfrag vb_l0 = *(const bfrag*)(BTlo + (size_t)bn0 * K + k0 + akc);
        bfrag vb_h1 = *(const bfrag*)(BThi + (size_t)bn1 * K + k0 + akc);
        bfrag vb_l1 = *(const bfrag*)(BTlo + (size_t)bn1 * K + k0 + akc);
        __syncthreads();
        *(bfrag*)&sA[0][arow][akc]      = va_h;
        *(bfrag*)&sA[1][arow][akc]      = va_l;
        *(bfrag*)&sB[0][arow][akc]      = vb_h0;
        *(bfrag*)&sB[1][arow][akc]      = vb_l0;
        *(bfrag*)&sB[0][64 + arow][akc] = vb_h1;
        *(bfrag*)&sB[1][64 + arow][akc] = vb_l1;
        __syncthreads();
        bfrag ah[2], al_[2], bh[4], bl[4];
        #pragma unroll
        for (int mt = 0; mt < 2; mt++) {
            ah[mt]  = *(const bfrag*)&sA[0][wm * 32 + mt * 16 + c16][kq * 8];
            al_[mt] = *(const bfrag*)&sA[1][wm * 32 + mt * 16 + c16][kq * 8];
        }
        #pragma unroll
        for (int nt = 0; nt < 4; nt++) {
            bh[nt] = *(const bfrag*)&sB[0][wn * 64 + nt * 16 + c16][kq * 8];
            bl[nt] = *(const bfrag*)&sB[1][wn * 64 + nt * 16 + c16][kq * 8];
        }
        #pragma unroll
        for (int mt = 0; mt < 2; mt++)
            #pragma unroll
            for (int nt = 0; nt < 4; nt++) {
                acc[mt][nt] = __builtin_amdgcn_mfma_f32_16x16x32_bf16(ah[mt],  bh[nt], acc[mt][nt], 0, 0, 0);
                acc[mt][nt] = __builtin_amdgcn_mfma_f32_16x16x32_bf16(ah[mt],  bl[nt], acc[mt][nt], 0, 0, 0);
                acc[mt][nt] = __builtin_amdgcn_mfma_f32_16x16x32_bf16(al_[mt], bh[nt], acc[mt][nt], 0, 0, 0);
            }
    }
    #pragma unroll
    for (int mt = 0; mt < 2; mt++) {
        #pragma unroll
        for (int r = 0; r < 4; r++) {
            int row = m0 + wm * 32 + mt * 16 + kq * 4 + r;
            if (row < M) {
                #pragma unroll
                for (int nt = 0; nt < 4; nt++) {
                    int col = n0 + wn * 64 + nt * 16 + c16;
                    if (col < N) C[(size_t)row * N + col] = acc[mt][nt][r];
                }
            }
        }
    }
}

// ---------------------------------------------------------------------------
// Attention scores (unchanged)
// ---------------------------------------------------------------------------
template <int H>
__global__ __launch_bounds__(256) void att_k(const float* __restrict__ h,
                                             const float* __restrict__ att_s,
                                             const float* __restrict__ att_d,
                                             float* __restrict__ a_s,
                                             float* __restrict__ a_d, int N) {
    int w = (blockIdx.x * blockDim.x + threadIdx.x) >> 6;
    int lane = threadIdx.x & 63;
    if (w >= N * H) return;
    int n = w / H, hh = w % H;
    float v = h[(size_t)n * (H * 64) + hh * 64 + lane];
    float ss = v * att_s[hh * 64 + lane];
    float sd = v * att_d[hh * 64 + lane];
    #pragma unroll
    for (int off = 32; off; off >>= 1) {
        ss += __shfl_xor(ss, off);
        sd += __shfl_xor(sd, off);
    }
    if (lane == 0) { a_s[w] = ss; a_d[w] = sd; }
}

__device__ __forceinline__ float wave_max_f(float v) {
    #pragma unroll
    for (int off = 32; off; off >>= 1) v = fmaxf(v, __shfl_xor(v, off));
    return v;
}
__device__ __forceinline__ float wave_sum_f(float v) {
    #pragma unroll
    for (int off = 32; off; off >>= 1) v += __shfl_xor(v, off);
    return v;
}

// ---------------------------------------------------------------------------
// Aggregation: ONE WAVE per node, ALL heads at once.
// Lane L owns F=H consecutive columns (one head: h = L/(64/H)).
// Softmax once per node; alpha[h][jj] staged in per-wave LDS ([H][65] pad —
// conflict-free reads, broadcast in 8-lane groups). Per edge: readlane(src) +
// ds_read_b32(alpha) + 2x global dwordx4 + 8 FMA. Head-mean via xor-shuffle,
// BN pre-folded into scale/shift.
// ---------------------------------------------------------------------------
template <int H, bool MEAN_BN>
__global__ __launch_bounds__(256) void agg_k(
    const float* __restrict__ hfeat,
    const float* __restrict__ a_s, const float* __restrict__ a_d,
    const int* __restrict__ rowptr, const int* __restrict__ csr,
    const float* __restrict__ scale,   // MEAN_BN: folded BN scale; else unused
    const float* __restrict__ shift,   // MEAN_BN: folded BN shift; else bias
    float* __restrict__ outf, int N) {
    constexpr int OUT = H * 64;
    constexpr int F = H;          // floats per lane
    constexpr int G = 64 / H;     // lanes per head
    __shared__ float alpha_s[4][H][65];
    const int wv = threadIdx.x >> 6;
    const int lane = threadIdx.x & 63;
    const int node = blockIdx.x * 4 + wv;
    if (node >= N) return;        // no __syncthreads in this kernel — safe

    const int row = rowptr[node];
    const int deg = rowptr[node + 1] - row;
    const int hl = lane / G;

    float adn[H];
    #pragma unroll
    for (int h = 0; h < H; h++) adn[h] = a_d[(size_t)node * H + h];

    float acc[F] = {};

    if (deg <= 64) {
        // ---- fast path: single chunk, e cached in registers ----
        int s = 0;
        float e[H];
        #pragma unroll
        for (int h = 0; h < H; h++) e[h] = -INFINITY;
        if (lane < deg) {
            s = csr[row + lane];
            const float* ap = a_s + (size_t)s * H;
            if constexpr (H >= 4) {
                #pragma unroll
                for (int h4 = 0; h4 < H; h4 += 4) {
                    float4 av = *(const float4*)(ap + h4);
                    e[h4 + 0] = av.x + adn[h4 + 0];
                    e[h4 + 1] = av.y + adn[h4 + 1];
                    e[h4 + 2] = av.z + adn[h4 + 2];
                    e[h4 + 3] = av.w + adn[h4 + 3];
                }
            } else {
                e[0] = ap[0] + adn[0];
            }
            #pragma unroll
            for (int h = 0; h < H; h++) e[h] = e[h] > 0.f ? e[h] : 0.2f * e[h];
        }
        float m[H], p[H], inv[H];
        #pragma unroll
        for (int h = 0; h < H; h++) m[h] = wave_max_f(e[h]);
        #pragma unroll
        for (int h = 0; h < H; h++) p[h] = (lane < deg) ? __expf(e[h] - m[h]) : 0.f;
        #pragma unroll
        for (int h = 0; h < H; h++) inv[h] = 1.f / (wave_sum_f(p[h]) + 1e-16f);
        if (lane < deg) {
            #pragma unroll
            for (int h = 0; h < H; h++) alpha_s[wv][h][lane] = p[h] * inv[h];
        }
        asm volatile("s_waitcnt lgkmcnt(0)" ::: "memory");
        for (int jj = 0; jj < deg; jj++) {
            int ss = __builtin_amdgcn_readlane(s, jj);
            float al = alpha_s[wv][hl][jj];
            const float* rp = hfeat + (size_t)ss * OUT + lane * F;
            if constexpr (F >= 4) {
                #pragma unroll
                for (int i = 0; i < F; i += 4) {
                    float4 v = *(const float4*)(rp + i);
                    acc[i + 0] = fmaf(al, v.x, acc[i + 0]);
                    acc[i + 1] = fmaf(al, v.y, acc[i + 1]);
                    acc[i + 2] = fmaf(al, v.z, acc[i + 2]);
                    acc[i + 3] = fmaf(al, v.w, acc[i + 3]);
                }
            } else {
                acc[0] = fmaf(al, rp[0], acc[0]);
            }
        }
    } else {
        // ---- general path: chunked ----
        float m[H];
        #pragma unroll
        for (int h = 0; h < H; h++) m[h] = -INFINITY;
        for (int c0 = 0; c0 < deg; c0 += 64) {
            int j = c0 + lane;
            if (j < deg) {
                int s2 = csr[row + j];
                #pragma unroll
                for (int h = 0; h < H; h++) {
                    float e = a_s[(size_t)s2 * H + h] + adn[h];
                    e = e > 0.f ? e : 0.2f * e;
                    m[h] = fmaxf(m[h], e);
                }
            }
        }
        #pragma unroll
        for (int h = 0; h < H; h++) m[h] = wave_max_f(m[h]);
        float dsum[H] = {};
        for (int c0 = 0; c0 < deg; c0 += 64) {
            int j = c0 + lane;
            if (j < deg) {
                int s2 = csr[row + j];
                #pragma unroll
                for (int h = 0; h < H; h++) {
                    float e = a_s[(size_t)s2 * H + h] + adn[h];
                    e = e > 0.f ? e : 0.2f * e;
                    dsum[h] += __expf(e - m[h]);
                }
            }
        }
        float inv[H];
        #pragma unroll
        for (int h = 0; h < H; h++) inv[h] = 1.f / (wave_sum_f(dsum[h]) + 1e-16f);
        for (int c0 = 0; c0 < deg; c0 += 64) {
            int j = c0 + lane;
            int cnt = min(64, deg - c0);
            int s = 0;
            if (j < deg) {
                s = csr[row + j];
                #pragma unroll
                for (int h = 0; h < H; h++) {
                    float e = a_s[(size_t)s * H + h] + adn[h];
                    e = e > 0.f ? e : 0.2f * e;
                    alpha_s[wv][h][lane] = __expf(e - m[h]) * inv[h];
                }
            }
            asm volatile("s_waitcnt lgkmcnt(0)" ::: "memory");
            for (int jj = 0; jj < cnt; jj++) {
                int ss = __builtin_amdgcn_readlane(s, jj);
                float al = alpha_s[wv][hl][jj];
                const float* rp = hfeat + (size_t)ss * OUT + lane * F;
                if constexpr (F >= 4) {
                    #pragma unroll
                    for (int i = 0; i < F; i += 4) {
                        float4 v = *(const float4*)(rp + i);
                        acc[i + 0] = fmaf(al, v.x, acc[i + 0]);
                        acc[i + 1] = fmaf(al, v.y, acc[i + 1]);
                        acc[i + 2] = fmaf(al, v.z, acc[i + 2]);
                        acc[i + 3] = fmaf(al, v.w, acc[i + 3]);
                    }
                } else {
                    acc[0] = fmaf(al, rp[0], acc[0]);
                }
            }
            asm volatile("s_waitcnt lgkmcnt(0)" ::: "memory");
        }
    }

    if constexpr (MEAN_BN) {
        // head-mean: col(L,i) = L*F+i; output c = (L%G)*F+i; reduce over lanes
        // differing in bits >= log2(G)
        #pragma unroll
        for (int i = 0; i < F; i++) {
            #pragma unroll
            for (int msk = G; msk < 64; msk <<= 1)
                acc[i] += __shfl_xor(acc[i], msk);
        }
        if (lane < G) {
            int c0 = lane * F;
            float res[F];
            #pragma unroll
            for (int i = 0; i < F; i++) {
                float v = fmaf(acc[i] * (1.0f / H), scale[c0 + i], shift[c0 + i]);
                res[i] = fmaxf(v, 0.f);
            }
            #pragma unroll
            for (int i = 0; i < F; i += 4)
                *(float4*)(outf + (size_t)node * 64 + c0 + i) =
                    make_float4(res[i], res[i + 1], res[i + 2], res[i + 3]);
        }
    } else {
        outf[(size_t)node * 64 + lane] = acc[0] + shift[lane];
    }
}

// ---------------------------------------------------------------------------
// Classifier + softmax (unchanged)
// ---------------------------------------------------------------------------
__global__ __launch_bounds__(256) void cls_k(const float* __restrict__ feat,
                                             const float* __restrict__ cW1,
                                             const float* __restrict__ cb1,
                                             const float* __restrict__ cW2,
                                             const float* __restrict__ cb2,
                                             float* __restrict__ out, int N) {
    int lane = threadIdx.x & 63;
    int n = (blockIdx.x * blockDim.x + threadIdx.x) >> 6;
    if (n >= N) return;
    float hv = feat[(size_t)n * 64 + lane];
    float z = cb1[lane];
    #pragma unroll
    for (int k = 0; k < 64; k++) {
        float a = __shfl(hv, k);
        z = fmaf(a, cW1[k * 64 + lane], z);
    }
    z = fmaxf(z, 0.f);
    float lg = (lane < N_CLS) ? cb2[lane] : -INFINITY;
    #pragma unroll
    for (int k = 0; k < 64; k++) {
        float a = __shfl(z, k);
        if (lane < N_CLS) lg = fmaf(a, cW2[k * N_CLS + lane], lg);
    }
    float m = lg;
    #pragma unroll
    for (int off = 32; off; off >>= 1) m = fmaxf(m, __shfl_xor(m, off));
    float p = (lane < N_CLS) ? __expf(lg - m) : 0.f;
    float s = p;
    #pragma unroll
    for (int off = 32; off; off >>= 1) s += __shfl_xor(s, off);
    if (lane < N_CLS) out[(size_t)n * N_CLS + lane] = p / s;
}

// ---------------------------------------------------------------------------
extern "C" void kernel_launch(void* const* d_in, const int* in_sizes, int n_in,
                              void* d_out, int out_size, void* d_ws, size_t ws_size,
                              hipStream_t stream) {
    const int N = NN, E = EE, E2 = EE + NN;
    const float* x    = (const float*)d_in[0];
    const int*   ei   = (const int*)d_in[1];
    const float* W1   = (const float*)d_in[2];
    const float* as1  = (const float*)d_in[3];
    const float* ad1  = (const float*)d_in[4];
    const float* b1   = (const float*)d_in[5];
    const float* W2   = (const float*)d_in[6];
    const float* as2  = (const float*)d_in[7];
    const float* ad2  = (const float*)d_in[8];
    const float* b2   = (const float*)d_in[9];
    const float* W3   = (const float*)d_in[10];
    const float* as3  = (const float*)d_in[11];
    const float* ad3  = (const float*)d_in[12];
    const float* b3   = (const float*)d_in[13];
    const float* bn1g = (const float*)d_in[14];
    const float* bn1b = (const float*)d_in[15];
    const float* bn1m = (const float*)d_in[16];
    const float* bn1v = (const float*)d_in[17];
    const float* bn2g = (const float*)d_in[18];
    const float* bn2b = (const float*)d_in[19];
    const float* bn2m = (const float*)d_in[20];
    const float* bn2v = (const float*)d_in[21];
    const float* cW1  = (const float*)d_in[22];
    const float* cb1  = (const float*)d_in[23];
    const float* cW2  = (const float*)d_in[24];
    const float* cb2  = (const float*)d_in[25];
    float* out = (float*)d_out;

    char* ws = (char*)d_ws;
    size_t off = 0;
    auto alloc = [&](size_t bytes) {
        void* p = ws + off;
        off = (off + bytes + 255) & ~(size_t)255;
        return p;
    };
    int*   rowptr = (int*)alloc((size_t)(N + 1) * 4);
    int*   cursor = (int*)alloc((size_t)N * 4);
    int*   csr    = (int*)alloc((size_t)E2 * 4);
    float* hbig   = (float*)alloc((size_t)N * 512 * 4);
    float* asb    = (float*)alloc((size_t)N * 8 * 4);
    float* adb    = (float*)alloc((size_t)N * 8 * 4);
    float* f1     = (float*)alloc((size_t)N * 64 * 4);   // reused as f3
    float* f2     = (float*)alloc((size_t)N * 64 * 4);
    unsigned short* ahi = (unsigned short*)alloc((size_t)N * D_IN * 2);
    unsigned short* alo = (unsigned short*)alloc((size_t)N * D_IN * 2);
    unsigned short* wthi = (unsigned short*)alloc((size_t)512 * 256 * 2);
    unsigned short* wtlo = (unsigned short*)alloc((size_t)512 * 256 * 2);
    float* sc1 = (float*)alloc(64 * 4);
    float* sh1 = (float*)alloc(64 * 4);
    float* sc2 = (float*)alloc(64 * 4);
    float* sh2 = (float*)alloc(64 * 4);
    float* f3 = f1;

    // ---- CSR build + BN fold ----
    zero_k<<<(N + 255) / 256, 256, 0, stream>>>(cursor, N);
    count_k<<<(E2 + 255) / 256, 256, 0, stream>>>(ei, cursor, E, N);
    scan_k<<<1, 1024, 0, stream>>>(cursor, rowptr, N);
    zero_k<<<(N + 255) / 256, 256, 0, stream>>>(cursor, N);
    fill_k<<<(E2 + 255) / 256, 256, 0, stream>>>(ei, rowptr, cursor, csr, E, N);
    bnprep_k<<<1, 64, 0, stream>>>(bn1g, bn1b, bn1m, bn1v, b1, sc1, sh1);
    bnprep_k<<<1, 64, 0, stream>>>(bn2g, bn2b, bn2m, bn2v, b2, sc2, sh2);

    const int MB = (N + 63) / 64;
    const int AB = (N + 3) / 4;

    // ---- Layer 1: heads=8, in=256, concat=False + BN1 + ReLU ----
    cvt_a_k<<<((size_t)N * 256 + 255) / 256, 256, 0, stream>>>(x, ahi, alo, N * 256);
    cvt_bt_k<<<(256 * 512 + 255) / 256, 256, 0, stream>>>(W1, wthi, wtlo, 256, 512);
    gemm_mfma_k<<<dim3(4, MB), 256, 0, stream>>>(ahi, alo, wthi, wtlo, hbig, N, 512, 256);
    att_k<8><<<((size_t)N * 8 * 64 + 255) / 256, 256, 0, stream>>>(hbig, as1, ad1, asb, adb, N);
    agg_k<8, true><<<AB, 256, 0, stream>>>(hbig, asb, adb, rowptr, csr, sc1, sh1, f1, N);

    // ---- Layer 2: heads=4, in=64, concat=False + BN2 + ReLU ----
    cvt_a_k<<<((size_t)N * 64 + 255) / 256, 256, 0, stream>>>(f1, ahi, alo, N * 64);
    cvt_bt_k<<<(64 * 256 + 255) / 256, 256, 0, stream>>>(W2, wthi, wtlo, 64, 256);
    gemm_mfma_k<<<dim3(2, MB), 256, 0, stream>>>(ahi, alo, wthi, wtlo, hbig, N, 256, 64);
    att_k<4><<<((size_t)N * 4 * 64 + 255) / 256, 256, 0, stream>>>(hbig, as2, ad2, asb, adb, N);
    agg_k<4, true><<<AB, 256, 0, stream>>>(hbig, asb, adb, rowptr, csr, sc2, sh2, f2, N);

    // ---- Layer 3: heads=1, in=64, concat=True ----
    cvt_a_k<<<((size_t)N * 64 + 255) / 256, 256, 0, stream>>>(f2, ahi, alo, N * 64);
    cvt_bt_k<<<(64 * 64 + 255) / 256, 256, 0, stream>>>(W3, wthi, wtlo, 64, 64);
    gemm_mfma_k<<<dim3(1, MB), 256, 0, stream>>>(ahi, alo, wthi, wtlo, hbig, N, 64, 64);
    att_k<1><<<((size_t)N * 1 * 64 + 255) / 256, 256, 0, stream>>>(hbig, as3, ad3, asb, adb, N);
    agg_k<1, false><<<AB, 256, 0, stream>>>(hbig, asb, adb, rowptr, csr, nullptr, b3, f3, N);

    // ---- Classifier + softmax ----
    cls_k<<<(N + 3) / 4, 256, 0, stream>>>(f3, cW1, cb1, cW2, cb2, out, N);
}

// Round 4
// 742.873 us; speedup vs baseline: 1.4728x; 1.1476x over previous
//
#include <hip/hip_runtime.h>
#include <hip/hip_bf16.h>
#include <math.h>

#define NN 50000
#define EE 400000
#define D_IN 256
#define D_H 64
#define N_CLS 50

typedef __attribute__((ext_vector_type(8))) short bfrag;   // 8 bf16 (4 VGPR)
typedef __attribute__((ext_vector_type(4))) float ffrag;   // MFMA C/D

__device__ __forceinline__ unsigned short f2bf(float v) {
    unsigned int u = __float_as_uint(v);
    unsigned int r = (u + 0x7fffu + ((u >> 16) & 1u)) >> 16;   // RNE
    return (unsigned short)r;
}
__device__ __forceinline__ float bf2f(unsigned short b) {
    return __uint_as_float(((unsigned int)b) << 16);
}

// ---------------------------------------------------------------------------
// CSR construction (verified round 0)
// ---------------------------------------------------------------------------
__global__ void zero_k(int* p, int n) {
    int i = blockIdx.x * blockDim.x + threadIdx.x;
    if (i < n) p[i] = 0;
}

__global__ void count_k(const int* __restrict__ ei, int* __restrict__ cnt, int E, int N) {
    int i = blockIdx.x * blockDim.x + threadIdx.x;
    if (i >= E + N) return;
    int dst = (i < E) ? ei[E + i] : (i - E);
    atomicAdd(&cnt[dst], 1);
}

__global__ __launch_bounds__(1024) void scan_k(const int* __restrict__ counts,
                                               int* __restrict__ rowptr, int n) {
    __shared__ int wsum[16];
    __shared__ int carry_s;
    int t = threadIdx.x;
    int lane = t & 63, wid = t >> 6;
    if (t == 0) carry_s = 0;
    __syncthreads();
    for (int base = 0; base < n; base += 1024) {
        int idx = base + t;
        int v = (idx < n) ? counts[idx] : 0;
        int incl = v;
        #pragma unroll
        for (int off = 1; off < 64; off <<= 1) {
            int x = __shfl_up(incl, off);
            if (lane >= off) incl += x;
        }
        if (lane == 63) wsum[wid] = incl;
        __syncthreads();
        if (wid == 0) {
            int ws = (lane < 16) ? wsum[lane] : 0;
            int wincl = ws;
            #pragma unroll
            for (int off = 1; off < 16; off <<= 1) {
                int x = __shfl_up(wincl, off);
                if (lane >= off) wincl += x;
            }
            if (lane < 16) wsum[lane] = wincl - ws;
        }
        __syncthreads();
        int c = carry_s;
        if (idx < n) rowptr[idx] = c + wsum[wid] + (incl - v);
        __syncthreads();
        if (t == 1023) carry_s = c + wsum[15] + incl;
        __syncthreads();
    }
    if (t == 0) rowptr[n] = carry_s;
}

__global__ void fill_k(const int* __restrict__ ei, const int* __restrict__ rowptr,
                       int* __restrict__ cursor, int* __restrict__ csr, int E, int N) {
    int i = blockIdx.x * blockDim.x + threadIdx.x;
    if (i >= E + N) return;
    int s, d;
    if (i < E) { s = ei[i]; d = ei[E + i]; }
    else       { s = i - E; d = i - E; }
    int pos = atomicAdd(&cursor[d], 1);
    csr[rowptr[d] + pos] = s;
}

// ---------------------------------------------------------------------------
// Split-bf16 conversion kernels
// ---------------------------------------------------------------------------
__global__ void cvt_a_k(const float* __restrict__ a, unsigned short* __restrict__ hi,
                        unsigned short* __restrict__ lo, int n) {
    int i = blockIdx.x * 256 + threadIdx.x;
    if (i >= n) return;
    float v = a[i];
    unsigned short h = f2bf(v);
    hi[i] = h;
    lo[i] = f2bf(v - bf2f(h));
}

__global__ void cvt_bt_k(const float* __restrict__ Bsrc, unsigned short* __restrict__ hi,
                         unsigned short* __restrict__ lo, int K, int N) {
    int i = blockIdx.x * 256 + threadIdx.x;
    if (i >= K * N) return;
    int k = i / N, n = i % N;
    float v = Bsrc[i];
    unsigned short h = f2bf(v);
    hi[(size_t)n * K + k] = h;
    lo[(size_t)n * K + k] = f2bf(v - bf2f(h));
}

// BN folding: scale = g*rsqrt(v+eps); shift = (bias - m)*scale + b
__global__ void bnprep_k(const float* __restrict__ g, const float* __restrict__ b,
                         const float* __restrict__ m, const float* __restrict__ v,
                         const float* __restrict__ bias,
                         float* __restrict__ scale, float* __restrict__ shift) {
    int t = threadIdx.x;
    if (t < 64) {
        float sc = g[t] * rsqrtf(v[t] + 1e-5f);
        scale[t] = sc;
        shift[t] = (bias[t] - m[t]) * sc + b[t];
    }
}

// ---------------------------------------------------------------------------
// Split-bf16 MFMA GEMM: C[M,N] = A @ B (+bias, optional ReLU), B passed as B^T.
// ---------------------------------------------------------------------------
__global__ __launch_bounds__(256) void gemm_mfma_k(
    const unsigned short* __restrict__ Ahi, const unsigned short* __restrict__ Alo,
    const unsigned short* __restrict__ BThi, const unsigned short* __restrict__ BTlo,
    float* __restrict__ C, int M, int N, int K,
    const float* __restrict__ bias, int do_relu) {
    __shared__ unsigned short sA[2][64][40];
    __shared__ unsigned short sB[2][128][40];
    const int tid = threadIdx.x;
    const int m0 = blockIdx.y * 64;
    const int n0 = blockIdx.x * 128;
    const int lane = tid & 63, w = tid >> 6;
    const int wm = w >> 1, wn = w & 1;
    const int c16 = lane & 15, kq = lane >> 4;
    const int arow = tid >> 2;
    const int akc  = (tid & 3) * 8;
    const int aM  = min(m0 + arow, M - 1);
    const int bn0 = min(n0 + arow, N - 1);
    const int bn1 = min(n0 + 64 + arow, N - 1);
    ffrag acc[2][4] = {};

    for (int k0 = 0; k0 < K; k0 += 32) {
        bfrag va_h  = *(const bfrag*)(Ahi  + (size_t)aM  * K + k0 + akc);
        bfrag va_l  = *(const bfrag*)(Alo  + (size_t)aM  * K + k0 + akc);
        bfrag vb_h0 = *(const bfrag*)(BThi + (size_t)bn0 * K + k0 + akc);
        bfrag vb_l0 = *(const bfrag*)(BTlo + (size_t)bn0 * K + k0 + akc);
        bfrag vb_h1 = *(const bfrag*)(BThi + (size_t)bn1 * K + k0 + akc);
        bfrag vb_l1 = *(const bfrag*)(BTlo + (size_t)bn1 * K + k0 + akc);
        __syncthreads();
        *(bfrag*)&sA[0][arow][akc]      = va_h;
        *(bfrag*)&sA[1][arow][akc]      = va_l;
        *(bfrag*)&sB[0][arow][akc]      = vb_h0;
        *(bfrag*)&sB[1][arow][akc]      = vb_l0;
        *(bfrag*)&sB[0][64 + arow][akc] = vb_h1;
        *(bfrag*)&sB[1][64 + arow][akc] = vb_l1;
        __syncthreads();
        bfrag ah[2], al_[2], bh[4], bl[4];
        #pragma unroll
        for (int mt = 0; mt < 2; mt++) {
            ah[mt]  = *(const bfrag*)&sA[0][wm * 32 + mt * 16 + c16][kq * 8];
            al_[mt] = *(const bfrag*)&sA[1][wm * 32 + mt * 16 + c16][kq * 8];
        }
        #pragma unroll
        for (int nt = 0; nt < 4; nt++) {
            bh[nt] = *(const bfrag*)&sB[0][wn * 64 + nt * 16 + c16][kq * 8];
            bl[nt] = *(const bfrag*)&sB[1][wn * 64 + nt * 16 + c16][kq * 8];
        }
        #pragma unroll
        for (int mt = 0; mt < 2; mt++)
            #pragma unroll
            for (int nt = 0; nt < 4; nt++) {
                acc[mt][nt] = __builtin_amdgcn_mfma_f32_16x16x32_bf16(ah[mt],  bh[nt], acc[mt][nt], 0, 0, 0);
                acc[mt][nt] = __builtin_amdgcn_mfma_f32_16x16x32_bf16(ah[mt],  bl[nt], acc[mt][nt], 0, 0, 0);
                acc[mt][nt] = __builtin_amdgcn_mfma_f32_16x16x32_bf16(al_[mt], bh[nt], acc[mt][nt], 0, 0, 0);
            }
    }
    #pragma unroll
    for (int mt = 0; mt < 2; mt++) {
        #pragma unroll
        for (int r = 0; r < 4; r++) {
            int row = m0 + wm * 32 + mt * 16 + kq * 4 + r;
            if (row < M) {
                #pragma unroll
                for (int nt = 0; nt < 4; nt++) {
                    int col = n0 + wn * 64 + nt * 16 + c16;
                    if (col < N) {
                        float v = acc[mt][nt][r];
                        if (bias) v += bias[col];
                        if (do_relu) v = fmaxf(v, 0.f);
                        C[(size_t)row * N + col] = v;
                    }
                }
            }
        }
    }
}

// ---------------------------------------------------------------------------
// Attention scores
// ---------------------------------------------------------------------------
template <int H>
__global__ __launch_bounds__(256) void att_k(const float* __restrict__ h,
                                             const float* __restrict__ att_s,
                                             const float* __restrict__ att_d,
                                             float* __restrict__ a_s,
                                             float* __restrict__ a_d, int N) {
    int w = (blockIdx.x * blockDim.x + threadIdx.x) >> 6;
    int lane = threadIdx.x & 63;
    if (w >= N * H) return;
    int n = w / H, hh = w % H;
    float v = h[(size_t)n * (H * 64) + hh * 64 + lane];
    float ss = v * att_s[hh * 64 + lane];
    float sd = v * att_d[hh * 64 + lane];
    #pragma unroll
    for (int off = 32; off; off >>= 1) {
        ss += __shfl_xor(ss, off);
        sd += __shfl_xor(sd, off);
    }
    if (lane == 0) { a_s[w] = ss; a_d[w] = sd; }
}

__device__ __forceinline__ float wave_max_f(float v) {
    #pragma unroll
    for (int off = 32; off; off >>= 1) v = fmaxf(v, __shfl_xor(v, off));
    return v;
}
__device__ __forceinline__ float wave_sum_f(float v) {
    #pragma unroll
    for (int off = 32; off; off >>= 1) v += __shfl_xor(v, off);
    return v;
}

// ---------------------------------------------------------------------------
// Aggregation: ONE WAVE per node, ALL heads at once (verified round 3).
// ---------------------------------------------------------------------------
template <int H, bool MEAN_BN>
__global__ __launch_bounds__(256) void agg_k(
    const float* __restrict__ hfeat,
    const float* __restrict__ a_s, const float* __restrict__ a_d,
    const int* __restrict__ rowptr, const int* __restrict__ csr,
    const float* __restrict__ scale,   // MEAN_BN: folded BN scale; else unused
    const float* __restrict__ shift,   // MEAN_BN: folded BN shift; else bias
    float* __restrict__ outf, int N) {
    constexpr int OUT = H * 64;
    constexpr int F = H;          // floats per lane
    constexpr int G = 64 / H;     // lanes per head
    __shared__ float alpha_s[4][H][65];
    const int wv = threadIdx.x >> 6;
    const int lane = threadIdx.x & 63;
    const int node = blockIdx.x * 4 + wv;
    if (node >= N) return;        // no __syncthreads in this kernel — safe

    const int row = rowptr[node];
    const int deg = rowptr[node + 1] - row;
    const int hl = lane / G;

    float adn[H];
    #pragma unroll
    for (int h = 0; h < H; h++) adn[h] = a_d[(size_t)node * H + h];

    float acc[F] = {};

    if (deg <= 64) {
        int s = 0;
        float e[H];
        #pragma unroll
        for (int h = 0; h < H; h++) e[h] = -INFINITY;
        if (lane < deg) {
            s = csr[row + lane];
            const float* ap = a_s + (size_t)s * H;
            if constexpr (H >= 4) {
                #pragma unroll
                for (int h4 = 0; h4 < H; h4 += 4) {
                    float4 av = *(const float4*)(ap + h4);
                    e[h4 + 0] = av.x + adn[h4 + 0];
                    e[h4 + 1] = av.y + adn[h4 + 1];
                    e[h4 + 2] = av.z + adn[h4 + 2];
                    e[h4 + 3] = av.w + adn[h4 + 3];
                }
            } else {
                e[0] = ap[0] + adn[0];
            }
            #pragma unroll
            for (int h = 0; h < H; h++) e[h] = e[h] > 0.f ? e[h] : 0.2f * e[h];
        }
        float m[H], p[H], inv[H];
        #pragma unroll
        for (int h = 0; h < H; h++) m[h] = wave_max_f(e[h]);
        #pragma unroll
        for (int h = 0; h < H; h++) p[h] = (lane < deg) ? __expf(e[h] - m[h]) : 0.f;
        #pragma unroll
        for (int h = 0; h < H; h++) inv[h] = 1.f / (wave_sum_f(p[h]) + 1e-16f);
        if (lane < deg) {
            #pragma unroll
            for (int h = 0; h < H; h++) alpha_s[wv][h][lane] = p[h] * inv[h];
        }
        asm volatile("s_waitcnt lgkmcnt(0)" ::: "memory");
        for (int jj = 0; jj < deg; jj++) {
            int ss = __builtin_amdgcn_readlane(s, jj);
            float al = alpha_s[wv][hl][jj];
            const float* rp = hfeat + (size_t)ss * OUT + lane * F;
            if constexpr (F >= 4) {
                #pragma unroll
                for (int i = 0; i < F; i += 4) {
                    float4 v = *(const float4*)(rp + i);
                    acc[i + 0] = fmaf(al, v.x, acc[i + 0]);
                    acc[i + 1] = fmaf(al, v.y, acc[i + 1]);
                    acc[i + 2] = fmaf(al, v.z, acc[i + 2]);
                    acc[i + 3] = fmaf(al, v.w, acc[i + 3]);
                }
            } else {
                acc[0] = fmaf(al, rp[0], acc[0]);
            }
        }
    } else {
        float m[H];
        #pragma unroll
        for (int h = 0; h < H; h++) m[h] = -INFINITY;
        for (int c0 = 0; c0 < deg; c0 += 64) {
            int j = c0 + lane;
            if (j < deg) {
                int s2 = csr[row + j];
                #pragma unroll
                for (int h = 0; h < H; h++) {
                    float e = a_s[(size_t)s2 * H + h] + adn[h];
                    e = e > 0.f ? e : 0.2f * e;
                    m[h] = fmaxf(m[h], e);
                }
            }
        }
        #pragma unroll
        for (int h = 0; h < H; h++) m[h] = wave_max_f(m[h]);
        float dsum[H] = {};
        for (int c0 = 0; c0 < deg; c0 += 64) {
            int j = c0 + lane;
            if (j < deg) {
                int s2 = csr[row + j];
                #pragma unroll
                for (int h = 0; h < H; h++) {
                    float e = a_s[(size_t)s2 * H + h] + adn[h];
                    e = e > 0.f ? e : 0.2f * e;
                    dsum[h] += __expf(e - m[h]);
                }
            }
        }
        float inv[H];
        #pragma unroll
        for (int h = 0; h < H; h++) inv[h] = 1.f / (wave_sum_f(dsum[h]) + 1e-16f);
        for (int c0 = 0; c0 < deg; c0 += 64) {
            int j = c0 + lane;
            int cnt = min(64, deg - c0);
            int s = 0;
            if (j < deg) {
                s = csr[row + j];
                #pragma unroll
                for (int h = 0; h < H; h++) {
                    float e = a_s[(size_t)s * H + h] + adn[h];
                    e = e > 0.f ? e : 0.2f * e;
                    alpha_s[wv][h][lane] = __expf(e - m[h]) * inv[h];
                }
            }
            asm volatile("s_waitcnt lgkmcnt(0)" ::: "memory");
            for (int jj = 0; jj < cnt; jj++) {
                int ss = __builtin_amdgcn_readlane(s, jj);
                float al = alpha_s[wv][hl][jj];
                const float* rp = hfeat + (size_t)ss * OUT + lane * F;
                if constexpr (F >= 4) {
                    #pragma unroll
                    for (int i = 0; i < F; i += 4) {
                        float4 v = *(const float4*)(rp + i);
                        acc[i + 0] = fmaf(al, v.x, acc[i + 0]);
                        acc[i + 1] = fmaf(al, v.y, acc[i + 1]);
                        acc[i + 2] = fmaf(al, v.z, acc[i + 2]);
                        acc[i + 3] = fmaf(al, v.w, acc[i + 3]);
                    }
                } else {
                    acc[0] = fmaf(al, rp[0], acc[0]);
                }
            }
            asm volatile("s_waitcnt lgkmcnt(0)" ::: "memory");
        }
    }

    if constexpr (MEAN_BN) {
        #pragma unroll
        for (int i = 0; i < F; i++) {
            #pragma unroll
            for (int msk = G; msk < 64; msk <<= 1)
                acc[i] += __shfl_xor(acc[i], msk);
        }
        if (lane < G) {
            int c0 = lane * F;
            float res[F];
            #pragma unroll
            for (int i = 0; i < F; i++) {
                float v = fmaf(acc[i] * (1.0f / H), scale[c0 + i], shift[c0 + i]);
                res[i] = fmaxf(v, 0.f);
            }
            #pragma unroll
            for (int i = 0; i < F; i += 4)
                *(float4*)(outf + (size_t)node * 64 + c0 + i) =
                    make_float4(res[i], res[i + 1], res[i + 2], res[i + 3]);
        }
    } else {
        outf[(size_t)node * 64 + lane] = acc[0] + shift[lane];
    }
}

// ---------------------------------------------------------------------------
// Softmax over N_CLS logits, wave per node.
// ---------------------------------------------------------------------------
__global__ __launch_bounds__(256) void softmax_k(const float* __restrict__ logits,
                                                 float* __restrict__ out, int N) {
    int lane = threadIdx.x & 63;
    int n = (blockIdx.x * blockDim.x + threadIdx.x) >> 6;
    if (n >= N) return;
    float lg = (lane < N_CLS) ? logits[(size_t)n * N_CLS + lane] : -INFINITY;
    float m = wave_max_f(lg);
    float p = (lane < N_CLS) ? __expf(lg - m) : 0.f;
    float s = wave_sum_f(p);
    if (lane < N_CLS) out[(size_t)n * N_CLS + lane] = p / s;
}

// ---------------------------------------------------------------------------
extern "C" void kernel_launch(void* const* d_in, const int* in_sizes, int n_in,
                              void* d_out, int out_size, void* d_ws, size_t ws_size,
                              hipStream_t stream) {
    const int N = NN, E = EE, E2 = EE + NN;
    const float* x    = (const float*)d_in[0];
    const int*   ei   = (const int*)d_in[1];
    const float* W1   = (const float*)d_in[2];
    const float* as1  = (const float*)d_in[3];
    const float* ad1  = (const float*)d_in[4];
    const float* b1   = (const float*)d_in[5];
    const float* W2   = (const float*)d_in[6];
    const float* as2  = (const float*)d_in[7];
    const float* ad2  = (const float*)d_in[8];
    const float* b2   = (const float*)d_in[9];
    const float* W3   = (const float*)d_in[10];
    const float* as3  = (const float*)d_in[11];
    const float* ad3  = (const float*)d_in[12];
    const float* b3   = (const float*)d_in[13];
    const float* bn1g = (const float*)d_in[14];
    const float* bn1b = (const float*)d_in[15];
    const float* bn1m = (const float*)d_in[16];
    const float* bn1v = (const float*)d_in[17];
    const float* bn2g = (const float*)d_in[18];
    const float* bn2b = (const float*)d_in[19];
    const float* bn2m = (const float*)d_in[20];
    const float* bn2v = (const float*)d_in[21];
    const float* cW1  = (const float*)d_in[22];
    const float* cb1  = (const float*)d_in[23];
    const float* cW2  = (const float*)d_in[24];
    const float* cb2  = (const float*)d_in[25];
    float* out = (float*)d_out;

    char* ws = (char*)d_ws;
    size_t off = 0;
    auto alloc = [&](size_t bytes) {
        void* p = ws + off;
        off = (off + bytes + 255) & ~(size_t)255;
        return p;
    };
    int*   rowptr = (int*)alloc((size_t)(N + 1) * 4);
    int*   cursor = (int*)alloc((size_t)N * 4);
    int*   csr    = (int*)alloc((size_t)E2 * 4);
    float* hbig   = (float*)alloc((size_t)N * 512 * 4);
    float* asb    = (float*)alloc((size_t)N * 8 * 4);
    float* adb    = (float*)alloc((size_t)N * 8 * 4);
    float* f1     = (float*)alloc((size_t)N * 64 * 4);   // reused as f3
    float* f2     = (float*)alloc((size_t)N * 64 * 4);   // reused as z
    unsigned short* ahi = (unsigned short*)alloc((size_t)N * D_IN * 2);
    unsigned short* alo = (unsigned short*)alloc((size_t)N * D_IN * 2);
    unsigned short* wthi = (unsigned short*)alloc((size_t)512 * 256 * 2);
    unsigned short* wtlo = (unsigned short*)alloc((size_t)512 * 256 * 2);
    float* sc1 = (float*)alloc(64 * 4);
    float* sh1 = (float*)alloc(64 * 4);
    float* sc2 = (float*)alloc(64 * 4);
    float* sh2 = (float*)alloc(64 * 4);
    float* f3 = f1;
    float* zbuf = f2;
    float* logits = hbig;   // hbig free after layer-3 att; logits N*50 fits

    // ---- CSR build + BN fold ----
    zero_k<<<(N + 255) / 256, 256, 0, stream>>>(cursor, N);
    count_k<<<(E2 + 255) / 256, 256, 0, stream>>>(ei, cursor, E, N);
    scan_k<<<1, 1024, 0, stream>>>(cursor, rowptr, N);
    zero_k<<<(N + 255) / 256, 256, 0, stream>>>(cursor, N);
    fill_k<<<(E2 + 255) / 256, 256, 0, stream>>>(ei, rowptr, cursor, csr, E, N);
    bnprep_k<<<1, 64, 0, stream>>>(bn1g, bn1b, bn1m, bn1v, b1, sc1, sh1);
    bnprep_k<<<1, 64, 0, stream>>>(bn2g, bn2b, bn2m, bn2v, b2, sc2, sh2);

    const int MB = (N + 63) / 64;
    const int AB = (N + 3) / 4;

    // ---- Layer 1: heads=8, in=256, concat=False + BN1 + ReLU ----
    cvt_a_k<<<((size_t)N * 256 + 255) / 256, 256, 0, stream>>>(x, ahi, alo, N * 256);
    cvt_bt_k<<<(256 * 512 + 255) / 256, 256, 0, stream>>>(W1, wthi, wtlo, 256, 512);
    gemm_mfma_k<<<dim3(4, MB), 256, 0, stream>>>(ahi, alo, wthi, wtlo, hbig, N, 512, 256, nullptr, 0);
    att_k<8><<<((size_t)N * 8 * 64 + 255) / 256, 256, 0, stream>>>(hbig, as1, ad1, asb, adb, N);
    agg_k<8, true><<<AB, 256, 0, stream>>>(hbig, asb, adb, rowptr, csr, sc1, sh1, f1, N);

    // ---- Layer 2: heads=4, in=64, concat=False + BN2 + ReLU ----
    cvt_a_k<<<((size_t)N * 64 + 255) / 256, 256, 0, stream>>>(f1, ahi, alo, N * 64);
    cvt_bt_k<<<(64 * 256 + 255) / 256, 256, 0, stream>>>(W2, wthi, wtlo, 64, 256);
    gemm_mfma_k<<<dim3(2, MB), 256, 0, stream>>>(ahi, alo, wthi, wtlo, hbig, N, 256, 64, nullptr, 0);
    att_k<4><<<((size_t)N * 4 * 64 + 255) / 256, 256, 0, stream>>>(hbig, as2, ad2, asb, adb, N);
    agg_k<4, true><<<AB, 256, 0, stream>>>(hbig, asb, adb, rowptr, csr, sc2, sh2, f2, N);

    // ---- Layer 3: heads=1, in=64, concat=True ----
    cvt_a_k<<<((size_t)N * 64 + 255) / 256, 256, 0, stream>>>(f2, ahi, alo, N * 64);
    cvt_bt_k<<<(64 * 64 + 255) / 256, 256, 0, stream>>>(W3, wthi, wtlo, 64, 64);
    gemm_mfma_k<<<dim3(1, MB), 256, 0, stream>>>(ahi, alo, wthi, wtlo, hbig, N, 64, 64, nullptr, 0);
    att_k<1><<<((size_t)N * 1 * 64 + 255) / 256, 256, 0, stream>>>(hbig, as3, ad3, asb, adb, N);
    agg_k<1, false><<<AB, 256, 0, stream>>>(hbig, asb, adb, rowptr, csr, nullptr, b3, f3, N);

    // ---- Classifier: z = relu(f3@cW1+cb1); logits = z@cW2+cb2; softmax ----
    cvt_a_k<<<((size_t)N * 64 + 255) / 256, 256, 0, stream>>>(f3, ahi, alo, N * 64);
    cvt_bt_k<<<(64 * 64 + 255) / 256, 256, 0, stream>>>(cW1, wthi, wtlo, 64, 64);
    gemm_mfma_k<<<dim3(1, MB), 256, 0, stream>>>(ahi, alo, wthi, wtlo, zbuf, N, 64, 64, cb1, 1);
    cvt_a_k<<<((size_t)N * 64 + 255) / 256, 256, 0, stream>>>(zbuf, ahi, alo, N * 64);
    cvt_bt_k<<<(64 * N_CLS + 255) / 256, 256, 0, stream>>>(cW2, wthi, wtlo, 64, N_CLS);
    gemm_mfma_k<<<dim3(1, MB), 256, 0, stream>>>(ahi, alo, wthi, wtlo, logits, N, N_CLS, 64, cb2, 0);
    softmax_k<<<(N + 3) / 4, 256, 0, stream>>>(logits, out, N);
}

// Round 5
// 579.855 us; speedup vs baseline: 1.8869x; 1.2811x over previous
//
#include <hip/hip_runtime.h>
#include <hip/hip_bf16.h>
#include <math.h>

#define NN 50000
#define EE 400000
#define D_IN 256
#define D_H 64
#define N_CLS 50

typedef __attribute__((ext_vector_type(8))) short bfrag;   // 8 bf16 (4 VGPR)
typedef __attribute__((ext_vector_type(4))) float ffrag;   // MFMA C/D
typedef __attribute__((ext_vector_type(8))) unsigned short u16x8_t;
typedef __attribute__((ext_vector_type(4))) unsigned short u16x4_t;

__device__ __forceinline__ unsigned short f2bf(float v) {
    unsigned int u = __float_as_uint(v);
    unsigned int r = (u + 0x7fffu + ((u >> 16) & 1u)) >> 16;   // RNE
    return (unsigned short)r;
}
__device__ __forceinline__ float bf2f(unsigned short b) {
    return __uint_as_float(((unsigned int)b) << 16);
}

// ---------------------------------------------------------------------------
// CSR construction (verified round 0)
// ---------------------------------------------------------------------------
__global__ void zero_k(int* p, int n) {
    int i = blockIdx.x * blockDim.x + threadIdx.x;
    if (i < n) p[i] = 0;
}

__global__ void count_k(const int* __restrict__ ei, int* __restrict__ cnt, int E, int N) {
    int i = blockIdx.x * blockDim.x + threadIdx.x;
    if (i >= E + N) return;
    int dst = (i < E) ? ei[E + i] : (i - E);
    atomicAdd(&cnt[dst], 1);
}

__global__ __launch_bounds__(1024) void scan_k(const int* __restrict__ counts,
                                               int* __restrict__ rowptr, int n) {
    __shared__ int wsum[16];
    __shared__ int carry_s;
    int t = threadIdx.x;
    int lane = t & 63, wid = t >> 6;
    if (t == 0) carry_s = 0;
    __syncthreads();
    for (int base = 0; base < n; base += 1024) {
        int idx = base + t;
        int v = (idx < n) ? counts[idx] : 0;
        int incl = v;
        #pragma unroll
        for (int off = 1; off < 64; off <<= 1) {
            int x = __shfl_up(incl, off);
            if (lane >= off) incl += x;
        }
        if (lane == 63) wsum[wid] = incl;
        __syncthreads();
        if (wid == 0) {
            int ws = (lane < 16) ? wsum[lane] : 0;
            int wincl = ws;
            #pragma unroll
            for (int off = 1; off < 16; off <<= 1) {
                int x = __shfl_up(wincl, off);
                if (lane >= off) wincl += x;
            }
            if (lane < 16) wsum[lane] = wincl - ws;
        }
        __syncthreads();
        int c = carry_s;
        if (idx < n) rowptr[idx] = c + wsum[wid] + (incl - v);
        __syncthreads();
        if (t == 1023) carry_s = c + wsum[15] + incl;
        __syncthreads();
    }
    if (t == 0) rowptr[n] = carry_s;
}

__global__ void fill_k(const int* __restrict__ ei, const int* __restrict__ rowptr,
                       int* __restrict__ cursor, int* __restrict__ csr, int E, int N) {
    int i = blockIdx.x * blockDim.x + threadIdx.x;
    if (i >= E + N) return;
    int s, d;
    if (i < E) { s = ei[i]; d = ei[E + i]; }
    else       { s = i - E; d = i - E; }
    int pos = atomicAdd(&cursor[d], 1);
    csr[rowptr[d] + pos] = s;
}

// ---------------------------------------------------------------------------
// Split-bf16 conversion kernels (x and weights only now)
// ---------------------------------------------------------------------------
__global__ void cvt_a_k(const float* __restrict__ a, unsigned short* __restrict__ hi,
                        unsigned short* __restrict__ lo, int n) {
    int i = blockIdx.x * 256 + threadIdx.x;
    if (i >= n) return;
    float v = a[i];
    unsigned short h = f2bf(v);
    hi[i] = h;
    lo[i] = f2bf(v - bf2f(h));
}

__global__ void cvt_bt_k(const float* __restrict__ Bsrc, unsigned short* __restrict__ hi,
                         unsigned short* __restrict__ lo, int K, int N) {
    int i = blockIdx.x * 256 + threadIdx.x;
    if (i >= K * N) return;
    int k = i / N, n = i % N;
    float v = Bsrc[i];
    unsigned short h = f2bf(v);
    hi[(size_t)n * K + k] = h;
    lo[(size_t)n * K + k] = f2bf(v - bf2f(h));
}

// BN folding: scale = g*rsqrt(v+eps); shift = (bias - m)*scale + b
__global__ void bnprep_k(const float* __restrict__ g, const float* __restrict__ b,
                         const float* __restrict__ m, const float* __restrict__ v,
                         const float* __restrict__ bias,
                         float* __restrict__ scale, float* __restrict__ shift) {
    int t = threadIdx.x;
    if (t < 64) {
        float sc = g[t] * rsqrtf(v[t] + 1e-5f);
        scale[t] = sc;
        shift[t] = (bias[t] - m[t]) * sc + b[t];
    }
}

// ---------------------------------------------------------------------------
// Split-bf16 MFMA GEMM with fused epilogues:
//  - optional fp32 C (Cf) and/or bf16 C (Chi [+ split-lo Clo])
//  - optional bias + ReLU
//  - optional fused GAT attention scores: each wave's 64-col slice is exactly
//    one head (heads are 64 wide, n0 multiple of 128) -> per-row dot with
//    att_s/att_d + 4 xor-shuffles (intra-16-lane), no atomics.
// ---------------------------------------------------------------------------
__global__ __launch_bounds__(256) void gemm_mfma_k(
    const unsigned short* __restrict__ Ahi, const unsigned short* __restrict__ Alo,
    const unsigned short* __restrict__ BThi, const unsigned short* __restrict__ BTlo,
    float* __restrict__ Cf, unsigned short* __restrict__ Chi, unsigned short* __restrict__ Clo,
    int M, int N, int K,
    const float* __restrict__ bias, int do_relu,
    const float* __restrict__ att_s, const float* __restrict__ att_d,
    float* __restrict__ asb, float* __restrict__ adb, int H) {
    __shared__ unsigned short sA[2][64][40];
    __shared__ unsigned short sB[2][128][40];
    const int tid = threadIdx.x;
    const int m0 = blockIdx.y * 64;
    const int n0 = blockIdx.x * 128;
    const int lane = tid & 63, w = tid >> 6;
    const int wm = w >> 1, wn = w & 1;
    const int c16 = lane & 15, kq = lane >> 4;
    const int arow = tid >> 2;
    const int akc  = (tid & 3) * 8;
    const int aM  = min(m0 + arow, M - 1);
    const int bn0 = min(n0 + arow, N - 1);
    const int bn1 = min(n0 + 64 + arow, N - 1);
    ffrag acc[2][4] = {};

    for (int k0 = 0; k0 < K; k0 += 32) {
        bfrag va_h  = *(const bfrag*)(Ahi  + (size_t)aM  * K + k0 + akc);
        bfrag va_l  = *(const bfrag*)(Alo  + (size_t)aM  * K + k0 + akc);
        bfrag vb_h0 = *(const bfrag*)(BThi + (size_t)bn0 * K + k0 + akc);
        bfrag vb_l0 = *(const bfrag*)(BTlo + (size_t)bn0 * K + k0 + akc);
        bfrag vb_h1 = *(const bfrag*)(BThi + (size_t)bn1 * K + k0 + akc);
        bfrag vb_l1 = *(const bfrag*)(BTlo + (size_t)bn1 * K + k0 + akc);
        __syncthreads();
        *(bfrag*)&sA[0][arow][akc]      = va_h;
        *(bfrag*)&sA[1][arow][akc]      = va_l;
        *(bfrag*)&sB[0][arow][akc]      = vb_h0;
        *(bfrag*)&sB[1][arow][akc]      = vb_l0;
        *(bfrag*)&sB[0][64 + arow][akc] = vb_h1;
        *(bfrag*)&sB[1][64 + arow][akc] = vb_l1;
        __syncthreads();
        bfrag ah[2], al_[2], bh[4], bl[4];
        #pragma unroll
        for (int mt = 0; mt < 2; mt++) {
            ah[mt]  = *(const bfrag*)&sA[0][wm * 32 + mt * 16 + c16][kq * 8];
            al_[mt] = *(const bfrag*)&sA[1][wm * 32 + mt * 16 + c16][kq * 8];
        }
        #pragma unroll
        for (int nt = 0; nt < 4; nt++) {
            bh[nt] = *(const bfrag*)&sB[0][wn * 64 + nt * 16 + c16][kq * 8];
            bl[nt] = *(const bfrag*)&sB[1][wn * 64 + nt * 16 + c16][kq * 8];
        }
        #pragma unroll
        for (int mt = 0; mt < 2; mt++)
            #pragma unroll
            for (int nt = 0; nt < 4; nt++) {
                acc[mt][nt] = __builtin_amdgcn_mfma_f32_16x16x32_bf16(ah[mt],  bh[nt], acc[mt][nt], 0, 0, 0);
                acc[mt][nt] = __builtin_amdgcn_mfma_f32_16x16x32_bf16(ah[mt],  bl[nt], acc[mt][nt], 0, 0, 0);
                acc[mt][nt] = __builtin_amdgcn_mfma_f32_16x16x32_bf16(al_[mt], bh[nt], acc[mt][nt], 0, 0, 0);
            }
    }

    // ---- fused attention scores (raw h, pre-bias/relu; GAT layers only) ----
    if (att_s) {
        int hidx = n0 / 64 + wn;
        if (hidx < H) {
            float s_att[4], d_att[4];
            #pragma unroll
            for (int nt = 0; nt < 4; nt++) {
                s_att[nt] = att_s[hidx * 64 + nt * 16 + c16];
                d_att[nt] = att_d[hidx * 64 + nt * 16 + c16];
            }
            #pragma unroll
            for (int mt = 0; mt < 2; mt++) {
                #pragma unroll
                for (int r = 0; r < 4; r++) {
                    int row = m0 + wm * 32 + mt * 16 + kq * 4 + r;
                    float ps = 0.f, pd = 0.f;
                    #pragma unroll
                    for (int nt = 0; nt < 4; nt++) {
                        ps = fmaf(acc[mt][nt][r], s_att[nt], ps);
                        pd = fmaf(acc[mt][nt][r], d_att[nt], pd);
                    }
                    #pragma unroll
                    for (int msk = 1; msk < 16; msk <<= 1) {
                        ps += __shfl_xor(ps, msk);
                        pd += __shfl_xor(pd, msk);
                    }
                    if (c16 == 0 && row < M) {
                        asb[(size_t)row * H + hidx] = ps;
                        adb[(size_t)row * H + hidx] = pd;
                    }
                }
            }
        }
    }

    // ---- C write ----
    #pragma unroll
    for (int mt = 0; mt < 2; mt++) {
        #pragma unroll
        for (int r = 0; r < 4; r++) {
            int row = m0 + wm * 32 + mt * 16 + kq * 4 + r;
            if (row < M) {
                #pragma unroll
                for (int nt = 0; nt < 4; nt++) {
                    int col = n0 + wn * 64 + nt * 16 + c16;
                    if (col < N) {
                        float v = acc[mt][nt][r];
                        if (bias) v += bias[col];
                        if (do_relu) v = fmaxf(v, 0.f);
                        size_t idx = (size_t)row * N + col;
                        if (Cf) Cf[idx] = v;
                        if (Chi) {
                            unsigned short hh = f2bf(v);
                            Chi[idx] = hh;
                            if (Clo) Clo[idx] = f2bf(v - bf2f(hh));
                        }
                    }
                }
            }
        }
    }
}

__device__ __forceinline__ float wave_max_f(float v) {
    #pragma unroll
    for (int off = 32; off; off >>= 1) v = fmaxf(v, __shfl_xor(v, off));
    return v;
}
__device__ __forceinline__ float wave_sum_f(float v) {
    #pragma unroll
    for (int off = 32; off; off >>= 1) v += __shfl_xor(v, off);
    return v;
}

// ---------------------------------------------------------------------------
// Aggregation: one wave per node, all heads. bf16 gather payload (halved
// traffic); output written as split hi/lo (exact) to feed the next GEMM.
// ---------------------------------------------------------------------------
template <int H, bool MEAN_BN>
__global__ __launch_bounds__(256) void agg_k(
    const unsigned short* __restrict__ hfeat,   // [N, H*64] bf16
    const float* __restrict__ a_s, const float* __restrict__ a_d,
    const int* __restrict__ rowptr, const int* __restrict__ csr,
    const float* __restrict__ scale,   // MEAN_BN: folded BN scale; else unused
    const float* __restrict__ shift,   // MEAN_BN: folded BN shift; else bias
    unsigned short* __restrict__ outhi, unsigned short* __restrict__ outlo,
    int N) {
    constexpr int OUT = H * 64;
    constexpr int F = H;          // channels per lane
    constexpr int G = 64 / H;     // lanes per head
    __shared__ float alpha_s[4][H][65];
    const int wv = threadIdx.x >> 6;
    const int lane = threadIdx.x & 63;
    const int node = blockIdx.x * 4 + wv;
    if (node >= N) return;        // no __syncthreads in this kernel — safe

    const int row = rowptr[node];
    const int deg = rowptr[node + 1] - row;
    const int hl = lane / G;

    float adn[H];
    #pragma unroll
    for (int h = 0; h < H; h++) adn[h] = a_d[(size_t)node * H + h];

    float acc[F] = {};

    if (deg <= 64) {
        int s = 0;
        float e[H];
        #pragma unroll
        for (int h = 0; h < H; h++) e[h] = -INFINITY;
        if (lane < deg) {
            s = csr[row + lane];
            const float* ap = a_s + (size_t)s * H;
            if constexpr (H >= 4) {
                #pragma unroll
                for (int h4 = 0; h4 < H; h4 += 4) {
                    float4 av = *(const float4*)(ap + h4);
                    e[h4 + 0] = av.x + adn[h4 + 0];
                    e[h4 + 1] = av.y + adn[h4 + 1];
                    e[h4 + 2] = av.z + adn[h4 + 2];
                    e[h4 + 3] = av.w + adn[h4 + 3];
                }
            } else {
                e[0] = ap[0] + adn[0];
            }
            #pragma unroll
            for (int h = 0; h < H; h++) e[h] = e[h] > 0.f ? e[h] : 0.2f * e[h];
        }
        float m[H], p[H], inv[H];
        #pragma unroll
        for (int h = 0; h < H; h++) m[h] = wave_max_f(e[h]);
        #pragma unroll
        for (int h = 0; h < H; h++) p[h] = (lane < deg) ? __expf(e[h] - m[h]) : 0.f;
        #pragma unroll
        for (int h = 0; h < H; h++) inv[h] = 1.f / (wave_sum_f(p[h]) + 1e-16f);
        if (lane < deg) {
            #pragma unroll
            for (int h = 0; h < H; h++) alpha_s[wv][h][lane] = p[h] * inv[h];
        }
        asm volatile("s_waitcnt lgkmcnt(0)" ::: "memory");
        for (int jj = 0; jj < deg; jj++) {
            int ss = __builtin_amdgcn_readlane(s, jj);
            float al = alpha_s[wv][hl][jj];
            const unsigned short* rp = hfeat + (size_t)ss * OUT + lane * F;
            if constexpr (F == 8) {
                u16x8_t u = *(const u16x8_t*)rp;
                #pragma unroll
                for (int i = 0; i < 8; i++) acc[i] = fmaf(al, bf2f(u[i]), acc[i]);
            } else if constexpr (F == 4) {
                u16x4_t u = *(const u16x4_t*)rp;
                #pragma unroll
                for (int i = 0; i < 4; i++) acc[i] = fmaf(al, bf2f(u[i]), acc[i]);
            } else {
                acc[0] = fmaf(al, bf2f(rp[0]), acc[0]);
            }
        }
    } else {
        float m[H];
        #pragma unroll
        for (int h = 0; h < H; h++) m[h] = -INFINITY;
        for (int c0 = 0; c0 < deg; c0 += 64) {
            int j = c0 + lane;
            if (j < deg) {
                int s2 = csr[row + j];
                #pragma unroll
                for (int h = 0; h < H; h++) {
                    float e = a_s[(size_t)s2 * H + h] + adn[h];
                    e = e > 0.f ? e : 0.2f * e;
                    m[h] = fmaxf(m[h], e);
                }
            }
        }
        #pragma unroll
        for (int h = 0; h < H; h++) m[h] = wave_max_f(m[h]);
        float dsum[H] = {};
        for (int c0 = 0; c0 < deg; c0 += 64) {
            int j = c0 + lane;
            if (j < deg) {
                int s2 = csr[row + j];
                #pragma unroll
                for (int h = 0; h < H; h++) {
                    float e = a_s[(size_t)s2 * H + h] + adn[h];
                    e = e > 0.f ? e : 0.2f * e;
                    dsum[h] += __expf(e - m[h]);
                }
            }
        }
        float inv[H];
        #pragma unroll
        for (int h = 0; h < H; h++) inv[h] = 1.f / (wave_sum_f(dsum[h]) + 1e-16f);
        for (int c0 = 0; c0 < deg; c0 += 64) {
            int j = c0 + lane;
            int cnt = min(64, deg - c0);
            int s = 0;
            if (j < deg) {
                s = csr[row + j];
                #pragma unroll
                for (int h = 0; h < H; h++) {
                    float e = a_s[(size_t)s * H + h] + adn[h];
                    e = e > 0.f ? e : 0.2f * e;
                    alpha_s[wv][h][lane] = __expf(e - m[h]) * inv[h];
                }
            }
            asm volatile("s_waitcnt lgkmcnt(0)" ::: "memory");
            for (int jj = 0; jj < cnt; jj++) {
                int ss = __builtin_amdgcn_readlane(s, jj);
                float al = alpha_s[wv][hl][jj];
                const unsigned short* rp = hfeat + (size_t)ss * OUT + lane * F;
                if constexpr (F == 8) {
                    u16x8_t u = *(const u16x8_t*)rp;
                    #pragma unroll
                    for (int i = 0; i < 8; i++) acc[i] = fmaf(al, bf2f(u[i]), acc[i]);
                } else if constexpr (F == 4) {
                    u16x4_t u = *(const u16x4_t*)rp;
                    #pragma unroll
                    for (int i = 0; i < 4; i++) acc[i] = fmaf(al, bf2f(u[i]), acc[i]);
                } else {
                    acc[0] = fmaf(al, bf2f(rp[0]), acc[0]);
                }
            }
            asm volatile("s_waitcnt lgkmcnt(0)" ::: "memory");
        }
    }

    if constexpr (MEAN_BN) {
        #pragma unroll
        for (int i = 0; i < F; i++) {
            #pragma unroll
            for (int msk = G; msk < 64; msk <<= 1)
                acc[i] += __shfl_xor(acc[i], msk);
        }
        if (lane < G) {
            int c0 = lane * F;
            #pragma unroll
            for (int i = 0; i < F; i++) {
                float v = fmaf(acc[i] * (1.0f / H), scale[c0 + i], shift[c0 + i]);
                v = fmaxf(v, 0.f);
                unsigned short hh = f2bf(v);
                outhi[(size_t)node * 64 + c0 + i] = hh;
                outlo[(size_t)node * 64 + c0 + i] = f2bf(v - bf2f(hh));
            }
        }
    } else {
        float v = acc[0] + shift[lane];
        unsigned short hh = f2bf(v);
        outhi[(size_t)node * 64 + lane] = hh;
        outlo[(size_t)node * 64 + lane] = f2bf(v - bf2f(hh));
    }
}

// ---------------------------------------------------------------------------
// Softmax over N_CLS logits, wave per node.
// ---------------------------------------------------------------------------
__global__ __launch_bounds__(256) void softmax_k(const float* __restrict__ logits,
                                                 float* __restrict__ out, int N) {
    int lane = threadIdx.x & 63;
    int n = (blockIdx.x * blockDim.x + threadIdx.x) >> 6;
    if (n >= N) return;
    float lg = (lane < N_CLS) ? logits[(size_t)n * N_CLS + lane] : -INFINITY;
    float m = wave_max_f(lg);
    float p = (lane < N_CLS) ? __expf(lg - m) : 0.f;
    float s = wave_sum_f(p);
    if (lane < N_CLS) out[(size_t)n * N_CLS + lane] = p / s;
}

// ---------------------------------------------------------------------------
extern "C" void kernel_launch(void* const* d_in, const int* in_sizes, int n_in,
                              void* d_out, int out_size, void* d_ws, size_t ws_size,
                              hipStream_t stream) {
    const int N = NN, E = EE, E2 = EE + NN;
    const float* x    = (const float*)d_in[0];
    const int*   ei   = (const int*)d_in[1];
    const float* W1   = (const float*)d_in[2];
    const float* as1  = (const float*)d_in[3];
    const float* ad1  = (const float*)d_in[4];
    const float* b1   = (const float*)d_in[5];
    const float* W2   = (const float*)d_in[6];
    const float* as2  = (const float*)d_in[7];
    const float* ad2  = (const float*)d_in[8];
    const float* b2   = (const float*)d_in[9];
    const float* W3   = (const float*)d_in[10];
    const float* as3  = (const float*)d_in[11];
    const float* ad3  = (const float*)d_in[12];
    const float* b3   = (const float*)d_in[13];
    const float* bn1g = (const float*)d_in[14];
    const float* bn1b = (const float*)d_in[15];
    const float* bn1m = (const float*)d_in[16];
    const float* bn1v = (const float*)d_in[17];
    const float* bn2g = (const float*)d_in[18];
    const float* bn2b = (const float*)d_in[19];
    const float* bn2m = (const float*)d_in[20];
    const float* bn2v = (const float*)d_in[21];
    const float* cW1  = (const float*)d_in[22];
    const float* cb1  = (const float*)d_in[23];
    const float* cW2  = (const float*)d_in[24];
    const float* cb2  = (const float*)d_in[25];
    float* out = (float*)d_out;

    char* ws = (char*)d_ws;
    size_t off = 0;
    auto alloc = [&](size_t bytes) {
        void* p = ws + off;
        off = (off + bytes + 255) & ~(size_t)255;
        return p;
    };
    int*   rowptr = (int*)alloc((size_t)(N + 1) * 4);
    int*   cursor = (int*)alloc((size_t)N * 4);
    int*   csr    = (int*)alloc((size_t)E2 * 4);
    unsigned short* hbf = (unsigned short*)alloc((size_t)N * 512 * 2);  // bf16 h
    float* asb    = (float*)alloc((size_t)N * 8 * 4);
    float* adb    = (float*)alloc((size_t)N * 8 * 4);
    unsigned short* xhi = (unsigned short*)alloc((size_t)N * D_IN * 2);
    unsigned short* xlo = (unsigned short*)alloc((size_t)N * D_IN * 2);
    unsigned short* f1h = (unsigned short*)alloc((size_t)N * 64 * 2);
    unsigned short* f1l = (unsigned short*)alloc((size_t)N * 64 * 2);
    unsigned short* f2h = (unsigned short*)alloc((size_t)N * 64 * 2);
    unsigned short* f2l = (unsigned short*)alloc((size_t)N * 64 * 2);
    unsigned short* f3h = (unsigned short*)alloc((size_t)N * 64 * 2);
    unsigned short* f3l = (unsigned short*)alloc((size_t)N * 64 * 2);
    unsigned short* zh  = (unsigned short*)alloc((size_t)N * 64 * 2);
    unsigned short* zl  = (unsigned short*)alloc((size_t)N * 64 * 2);
    unsigned short* wthi = (unsigned short*)alloc((size_t)512 * 256 * 2);
    unsigned short* wtlo = (unsigned short*)alloc((size_t)512 * 256 * 2);
    float* sc1 = (float*)alloc(64 * 4);
    float* sh1 = (float*)alloc(64 * 4);
    float* sc2 = (float*)alloc(64 * 4);
    float* sh2 = (float*)alloc(64 * 4);
    float* logits = (float*)alloc((size_t)N * N_CLS * 4);

    // ---- CSR build + BN fold ----
    zero_k<<<(N + 255) / 256, 256, 0, stream>>>(cursor, N);
    count_k<<<(E2 + 255) / 256, 256, 0, stream>>>(ei, cursor, E, N);
    scan_k<<<1, 1024, 0, stream>>>(cursor, rowptr, N);
    zero_k<<<(N + 255) / 256, 256, 0, stream>>>(cursor, N);
    fill_k<<<(E2 + 255) / 256, 256, 0, stream>>>(ei, rowptr, cursor, csr, E, N);
    bnprep_k<<<1, 64, 0, stream>>>(bn1g, bn1b, bn1m, bn1v, b1, sc1, sh1);
    bnprep_k<<<1, 64, 0, stream>>>(bn2g, bn2b, bn2m, bn2v, b2, sc2, sh2);

    const int MB = (N + 63) / 64;
    const int AB = (N + 3) / 4;

    // ---- Layer 1: heads=8, in=256 ----
    cvt_a_k<<<((size_t)N * 256 + 255) / 256, 256, 0, stream>>>(x, xhi, xlo, N * 256);
    cvt_bt_k<<<(256 * 512 + 255) / 256, 256, 0, stream>>>(W1, wthi, wtlo, 256, 512);
    gemm_mfma_k<<<dim3(4, MB), 256, 0, stream>>>(xhi, xlo, wthi, wtlo,
        nullptr, hbf, nullptr, N, 512, 256, nullptr, 0, as1, ad1, asb, adb, 8);
    agg_k<8, true><<<AB, 256, 0, stream>>>(hbf, asb, adb, rowptr, csr, sc1, sh1, f1h, f1l, N);

    // ---- Layer 2: heads=4, in=64 ----
    cvt_bt_k<<<(64 * 256 + 255) / 256, 256, 0, stream>>>(W2, wthi, wtlo, 64, 256);
    gemm_mfma_k<<<dim3(2, MB), 256, 0, stream>>>(f1h, f1l, wthi, wtlo,
        nullptr, hbf, nullptr, N, 256, 64, nullptr, 0, as2, ad2, asb, adb, 4);
    agg_k<4, true><<<AB, 256, 0, stream>>>(hbf, asb, adb, rowptr, csr, sc2, sh2, f2h, f2l, N);

    // ---- Layer 3: heads=1, in=64, concat ----
    cvt_bt_k<<<(64 * 64 + 255) / 256, 256, 0, stream>>>(W3, wthi, wtlo, 64, 64);
    gemm_mfma_k<<<dim3(1, MB), 256, 0, stream>>>(f2h, f2l, wthi, wtlo,
        nullptr, hbf, nullptr, N, 64, 64, nullptr, 0, as3, ad3, asb, adb, 1);
    agg_k<1, false><<<AB, 256, 0, stream>>>(hbf, asb, adb, rowptr, csr, nullptr, b3, f3h, f3l, N);

    // ---- Classifier: z = relu(f3@cW1+cb1) (split out) ; logits ; softmax ----
    cvt_bt_k<<<(64 * 64 + 255) / 256, 256, 0, stream>>>(cW1, wthi, wtlo, 64, 64);
    gemm_mfma_k<<<dim3(1, MB), 256, 0, stream>>>(f3h, f3l, wthi, wtlo,
        nullptr, zh, zl, N, 64, 64, cb1, 1, nullptr, nullptr, nullptr, nullptr, 0);
    cvt_bt_k<<<(64 * N_CLS + 255) / 256, 256, 0, stream>>>(cW2, wthi, wtlo, 64, N_CLS);
    gemm_mfma_k<<<dim3(1, MB), 256, 0, stream>>>(zh, zl, wthi, wtlo,
        logits, nullptr, nullptr, N, N_CLS, 64, cb2, 0, nullptr, nullptr, nullptr, nullptr, 0);
    softmax_k<<<(N + 3) / 4, 256, 0, stream>>>(logits, out, N);
}